// Round 1
// baseline (732.806 us; speedup 1.0000x reference)
//
#include <hip/hip_runtime.h>

#define N_NODES 100000
#define N_EDGES 1250000
#define IN_D 128
#define OUT_D 64

// ---- order-preserving float<->uint encoding for atomicMax on floats ----
__device__ __forceinline__ unsigned enc_f(float f) {
    unsigned u = __float_as_uint(f);
    return (u & 0x80000000u) ? ~u : (u | 0x80000000u);
}
__device__ __forceinline__ float dec_f(unsigned u) {
    return (u & 0x80000000u) ? __uint_as_float(u & 0x7fffffffu)
                             : __uint_as_float(~u);
}

// ---- K0: fused node projections z = x@W1^T, z_i = x@W2^T, plus per-node
//          attention scalars s1 = z.Wa[0:64], s2 = z.Wa[64:128].
//          One wave per node; W1^T/W2^T staged in LDS (lane-contiguous). ----
__global__ __launch_bounds__(256) void node_proj_kernel(
    const float* __restrict__ x, const float* __restrict__ W1,
    const float* __restrict__ W2, const float* __restrict__ Wa,
    float* __restrict__ z, float* __restrict__ zi,
    float* __restrict__ s1, float* __restrict__ s2)
{
    __shared__ float sW1[IN_D * OUT_D];   // transposed: sW1[j*64+k] = W1[k*128+j]
    __shared__ float sW2[IN_D * OUT_D];
    __shared__ float sWa[2 * OUT_D];
    __shared__ float sx[4][IN_D];

    for (int idx = threadIdx.x; idx < IN_D * OUT_D; idx += 256) {
        int k = idx >> 7, j = idx & 127;
        sW1[j * OUT_D + k] = W1[idx];
        sW2[j * OUT_D + k] = W2[idx];
    }
    if (threadIdx.x < 2 * OUT_D) sWa[threadIdx.x] = Wa[threadIdx.x];
    __syncthreads();

    const int wave = threadIdx.x >> 6;
    const int lane = threadIdx.x & 63;

    for (int n0 = blockIdx.x * 4; n0 < N_NODES; n0 += gridDim.x * 4) {
        const int n = n0 + wave;
        if (n < N_NODES) {
            // wave cooperatively loads its node's feature row (same-wave LDS
            // write->read: in-order at the LDS unit, no barrier needed)
            float2 v = ((const float2*)(x + (size_t)n * IN_D))[lane];
            ((float2*)sx[wave])[lane] = v;

            float acc1 = 0.f, acc2 = 0.f;
            #pragma unroll 8
            for (int j4 = 0; j4 < IN_D / 4; ++j4) {
                float4 xv = ((const float4*)sx[wave])[j4];
                acc1 += xv.x * sW1[(4*j4+0)*OUT_D + lane];
                acc1 += xv.y * sW1[(4*j4+1)*OUT_D + lane];
                acc1 += xv.z * sW1[(4*j4+2)*OUT_D + lane];
                acc1 += xv.w * sW1[(4*j4+3)*OUT_D + lane];
                acc2 += xv.x * sW2[(4*j4+0)*OUT_D + lane];
                acc2 += xv.y * sW2[(4*j4+1)*OUT_D + lane];
                acc2 += xv.z * sW2[(4*j4+2)*OUT_D + lane];
                acc2 += xv.w * sW2[(4*j4+3)*OUT_D + lane];
            }
            z [(size_t)n * OUT_D + lane] = acc1;
            zi[(size_t)n * OUT_D + lane] = acc2;

            // s1/s2 wave reductions (lane k holds z[n][k])
            float p1 = acc1 * sWa[lane];
            float p2 = acc1 * sWa[OUT_D + lane];
            #pragma unroll
            for (int off = 32; off > 0; off >>= 1) {
                p1 += __shfl_down(p1, off);
                p2 += __shfl_down(p2, off);
            }
            if (lane == 0) { s1[n] = p1; s2[n] = p2; }
        }
    }
}

// ---- K1: per-edge logit + leaky_relu + segment-max via encoded atomicMax ----
__global__ __launch_bounds__(256) void edge_logits_kernel(
    const float* __restrict__ edge_d, const int* __restrict__ src,
    const int* __restrict__ dst, const float* __restrict__ s1,
    const float* __restrict__ s2, const float* __restrict__ W0,
    const float* __restrict__ Wa, float* __restrict__ e_out,
    unsigned* __restrict__ m_enc)
{
    int i = blockIdx.x * 256 + threadIdx.x;
    if (i >= N_EDGES) return;
    const float c = W0[0] * Wa[2 * OUT_D];      // t-coefficient
    float a = s1[src[i]] + s2[dst[i]] + edge_d[i] * c;
    float e = (a > 0.f) ? a : 0.01f * a;        // leaky_relu slope 0.01
    e_out[i] = e;
    atomicMax(&m_enc[dst[i]], enc_f(e));
}

// ---- K2: wave-per-edge weighted scatter: accum[dst] += exp(e-m)*z[src],
//          denom[dst] += exp(e-m). Lane k handles feature k (coalesced). ----
__global__ __launch_bounds__(256) void edge_scatter_kernel(
    const int* __restrict__ src, const int* __restrict__ dst,
    const float* __restrict__ e_in, const unsigned* __restrict__ m_enc,
    const float* __restrict__ z, float* __restrict__ denom,
    float* __restrict__ accum)
{
    size_t gid = (size_t)blockIdx.x * 256 + threadIdx.x;
    int edge = (int)(gid >> 6);
    int lane = threadIdx.x & 63;
    if (edge >= N_EDGES) return;
    int s = src[edge], d = dst[edge];
    float m = dec_f(m_enc[d]);
    float ex = __expf(e_in[edge] - m);          // <= 1, no overflow
    if (lane == 0) unsafeAtomicAdd(&denom[d], ex);
    unsafeAtomicAdd(&accum[(size_t)d * OUT_D + lane],
                    ex * z[(size_t)s * OUT_D + lane]);
}

// ---- K3: h = relu(z_i + accum/denom), in-place on accum (=d_out) ----
__global__ __launch_bounds__(256) void finalize_kernel(
    const float4* __restrict__ zi4, const float* __restrict__ denom,
    float4* __restrict__ out4)
{
    int i = blockIdx.x * 256 + threadIdx.x;
    const int n4 = N_NODES * (OUT_D / 4);
    if (i >= n4) return;
    int n = i >> 4;                              // 16 float4 per node
    float dnm = denom[n];
    float inv = (dnm > 0.f) ? 1.f / dnm : 0.f;   // empty segment -> 0 (matches ref)
    float4 a = out4[i];
    float4 b = zi4[i];
    float h0 = b.x + a.x * inv, h1 = b.y + a.y * inv;
    float h2 = b.z + a.z * inv, h3 = b.w + a.w * inv;
    a.x = h0 > 0.f ? h0 : 0.f;
    a.y = h1 > 0.f ? h1 : 0.f;
    a.z = h2 > 0.f ? h2 : 0.f;
    a.w = h3 > 0.f ? h3 : 0.f;
    out4[i] = a;
}

extern "C" void kernel_launch(void* const* d_in, const int* in_sizes, int n_in,
                              void* d_out, int out_size, void* d_ws, size_t ws_size,
                              hipStream_t stream) {
    const float* node_feats = (const float*)d_in[0];
    const float* edge_d     = (const float*)d_in[1];
    const float* W0         = (const float*)d_in[2];
    const float* W1         = (const float*)d_in[3];
    const float* W2         = (const float*)d_in[4];
    const float* Wa         = (const float*)d_in[5];
    const int*   src        = (const int*)d_in[6];
    const int*   dst        = (const int*)d_in[7];
    float* out = (float*)d_out;

    // workspace layout
    char* ws = (char*)d_ws;
    float*    z     = (float*)ws;    ws += (size_t)N_NODES * OUT_D * 4;
    float*    zi    = (float*)ws;    ws += (size_t)N_NODES * OUT_D * 4;
    float*    s1    = (float*)ws;    ws += (size_t)N_NODES * 4;
    float*    s2    = (float*)ws;    ws += (size_t)N_NODES * 4;
    unsigned* m_enc = (unsigned*)ws; ws += (size_t)N_NODES * 4;
    float*    denom = (float*)ws;    ws += (size_t)N_NODES * 4;
    float*    e_buf = (float*)ws;    ws += (size_t)N_EDGES * 4;

    // accum lives in d_out; zero it + m_enc/denom (contiguous).
    // m_enc==0 decodes below every real encoding -> valid -inf sentinel.
    hipMemsetAsync(d_out, 0, (size_t)N_NODES * OUT_D * 4, stream);
    hipMemsetAsync(m_enc, 0, (size_t)N_NODES * 8, stream);

    node_proj_kernel<<<2048, 256, 0, stream>>>(node_feats, W1, W2, Wa, z, zi, s1, s2);

    edge_logits_kernel<<<(N_EDGES + 255) / 256, 256, 0, stream>>>(
        edge_d, src, dst, s1, s2, W0, Wa, e_buf, m_enc);

    size_t scatter_threads = (size_t)N_EDGES * 64;
    edge_scatter_kernel<<<(unsigned)((scatter_threads + 255) / 256), 256, 0, stream>>>(
        src, dst, e_buf, m_enc, z, denom, out);

    finalize_kernel<<<(N_NODES * (OUT_D / 4) + 255) / 256, 256, 0, stream>>>(
        (const float4*)zi, denom, (float4*)out);
}

// Round 2
// 576.669 us; speedup vs baseline: 1.2708x; 1.2708x over previous
//
#include <hip/hip_runtime.h>

#define N_NODES 100000
#define N_EDGES 1250000
#define IN_D 128
#define OUT_D 64
#define NB_NODES ((N_NODES + 255) / 256)   // 391
#define NB_EDGES ((N_EDGES + 255) / 256)   // 4883

// ---- K0: fused node projections z = x@W1^T, z_i = x@W2^T, plus per-node
//          attention scalars s1 = z.Wa[0:64], s2 = z.Wa[64:128].
//          One wave per node; W1^T/W2^T staged in LDS (lane-contiguous). ----
__global__ __launch_bounds__(256) void node_proj_kernel(
    const float* __restrict__ x, const float* __restrict__ W1,
    const float* __restrict__ W2, const float* __restrict__ Wa,
    float* __restrict__ z, float* __restrict__ zi,
    float* __restrict__ s1, float* __restrict__ s2)
{
    __shared__ float sW1[IN_D * OUT_D];   // transposed: sW1[j*64+k] = W1[k*128+j]
    __shared__ float sW2[IN_D * OUT_D];
    __shared__ float sWa[2 * OUT_D];
    __shared__ float sx[4][IN_D];

    for (int idx = threadIdx.x; idx < IN_D * OUT_D; idx += 256) {
        int k = idx >> 7, j = idx & 127;
        sW1[j * OUT_D + k] = W1[idx];
        sW2[j * OUT_D + k] = W2[idx];
    }
    if (threadIdx.x < 2 * OUT_D) sWa[threadIdx.x] = Wa[threadIdx.x];
    __syncthreads();

    const int wave = threadIdx.x >> 6;
    const int lane = threadIdx.x & 63;

    for (int n0 = blockIdx.x * 4; n0 < N_NODES; n0 += gridDim.x * 4) {
        const int n = n0 + wave;
        if (n < N_NODES) {
            float2 v = ((const float2*)(x + (size_t)n * IN_D))[lane];
            ((float2*)sx[wave])[lane] = v;   // same-wave LDS write->read, in-order

            float acc1 = 0.f, acc2 = 0.f;
            #pragma unroll 8
            for (int j4 = 0; j4 < IN_D / 4; ++j4) {
                float4 xv = ((const float4*)sx[wave])[j4];
                acc1 += xv.x * sW1[(4*j4+0)*OUT_D + lane];
                acc1 += xv.y * sW1[(4*j4+1)*OUT_D + lane];
                acc1 += xv.z * sW1[(4*j4+2)*OUT_D + lane];
                acc1 += xv.w * sW1[(4*j4+3)*OUT_D + lane];
                acc2 += xv.x * sW2[(4*j4+0)*OUT_D + lane];
                acc2 += xv.y * sW2[(4*j4+1)*OUT_D + lane];
                acc2 += xv.z * sW2[(4*j4+2)*OUT_D + lane];
                acc2 += xv.w * sW2[(4*j4+3)*OUT_D + lane];
            }
            z [(size_t)n * OUT_D + lane] = acc1;
            zi[(size_t)n * OUT_D + lane] = acc2;

            float p1 = acc1 * sWa[lane];
            float p2 = acc1 * sWa[OUT_D + lane];
            #pragma unroll
            for (int off = 32; off > 0; off >>= 1) {
                p1 += __shfl_down(p1, off);
                p2 += __shfl_down(p2, off);
            }
            if (lane == 0) { s1[n] = p1; s2[n] = p2; }
        }
    }
}

// ---- K1: in-degree histogram ----
__global__ __launch_bounds__(256) void histogram_kernel(
    const int* __restrict__ dst, int* __restrict__ deg)
{
    int i = blockIdx.x * 256 + threadIdx.x;
    if (i < N_EDGES) atomicAdd(&deg[dst[i]], 1);
}

// ---- K2a/b/c: exclusive scan of deg -> row_start (and cursor copy) ----
__global__ __launch_bounds__(256) void scan_reduce_kernel(
    const int* __restrict__ deg, int* __restrict__ partial)
{
    __shared__ int s[256];
    int t = threadIdx.x, idx = blockIdx.x * 256 + t;
    s[t] = (idx < N_NODES) ? deg[idx] : 0;
    __syncthreads();
    for (int off = 128; off > 0; off >>= 1) {
        if (t < off) s[t] += s[t + off];
        __syncthreads();
    }
    if (t == 0) partial[blockIdx.x] = s[0];
}

__global__ __launch_bounds__(512) void scan_partials_kernel(int* __restrict__ partial)
{
    __shared__ int s[512];
    int t = threadIdx.x;
    int v = (t < NB_NODES) ? partial[t] : 0;
    s[t] = v;
    __syncthreads();
    for (int off = 1; off < 512; off <<= 1) {
        int add = (t >= off) ? s[t - off] : 0;
        __syncthreads();
        s[t] += add;
        __syncthreads();
    }
    if (t < NB_NODES) partial[t] = s[t] - v;   // exclusive
}

__global__ __launch_bounds__(256) void scan_final_kernel(
    const int* __restrict__ deg, const int* __restrict__ partial,
    int* __restrict__ row_start, int* __restrict__ cursor)
{
    __shared__ int s[256];
    int t = threadIdx.x, idx = blockIdx.x * 256 + t;
    int v = (idx < N_NODES) ? deg[idx] : 0;
    s[t] = v;
    __syncthreads();
    for (int off = 1; off < 256; off <<= 1) {
        int add = (t >= off) ? s[t - off] : 0;
        __syncthreads();
        s[t] += add;
        __syncthreads();
    }
    int excl = s[t] - v + partial[blockIdx.x];
    if (idx < N_NODES) { row_start[idx] = excl; cursor[idx] = excl; }
}

// ---- K3: scatter edge ids into CSR lists ----
__global__ __launch_bounds__(256) void scatter_edges_kernel(
    const int* __restrict__ dst, int* __restrict__ cursor,
    int* __restrict__ edge_list)
{
    int i = blockIdx.x * 256 + threadIdx.x;
    if (i >= N_EDGES) return;
    int pos = atomicAdd(&cursor[dst[i]], 1);
    edge_list[pos] = i;
}

// ---- K4: wave-per-dst-node gather: inline logits, online softmax over the
//          node's edge list, weighted sum of z[src] rows, fused finalize. ----
__global__ __launch_bounds__(256) void gather_finalize_kernel(
    const int* __restrict__ edge_list, const int* __restrict__ row_start,
    const int* __restrict__ deg, const int* __restrict__ src,
    const float* __restrict__ edge_d, const float* __restrict__ s1,
    const float* __restrict__ s2, const float* __restrict__ W0,
    const float* __restrict__ Wa, const float* __restrict__ z,
    const float* __restrict__ zi, float* __restrict__ out)
{
    const float tc = W0[0] * Wa[2 * OUT_D];
    const int lane = threadIdx.x & 63;
    const int d = blockIdx.x * 4 + (threadIdx.x >> 6);
    if (d >= N_NODES) return;

    const int beg = row_start[d];
    const int dg  = deg[d];
    float acc = 0.f, den = 0.f;

    if (dg > 0) {
        const float s2d = s2[d];
        if (dg <= 64) {
            // single-chunk fast path: each lane owns one edge
            int   eid = (lane < dg) ? edge_list[beg + lane] : 0;
            int   sj  = (lane < dg) ? src[eid] : 0;
            float ej  = -INFINITY;
            if (lane < dg) {
                float a = s1[sj] + s2d + tc * edge_d[eid];
                ej = (a > 0.f) ? a : 0.01f * a;
            }
            float m = ej;
            #pragma unroll
            for (int off = 32; off > 0; off >>= 1) m = fmaxf(m, __shfl_xor(m, off));
            float exj = (lane < dg) ? __expf(ej - m) : 0.f;
            float ds = exj;
            #pragma unroll
            for (int off = 32; off > 0; off >>= 1) ds += __shfl_xor(ds, off);
            den = ds;
            for (int i = 0; i < dg; ++i) {
                int   s_i  = __shfl(sj, i);
                float ex_i = __shfl(exj, i);
                acc += ex_i * z[(size_t)s_i * OUT_D + lane];
            }
        } else {
            // general chunked two-pass path
            float m = -INFINITY;
            for (int c0 = 0; c0 < dg; c0 += 64) {
                int j = c0 + lane;
                float ej = -INFINITY;
                if (j < dg) {
                    int eid = edge_list[beg + j];
                    float a = s1[src[eid]] + s2d + tc * edge_d[eid];
                    ej = (a > 0.f) ? a : 0.01f * a;
                }
                #pragma unroll
                for (int off = 32; off > 0; off >>= 1) ej = fmaxf(ej, __shfl_xor(ej, off));
                m = fmaxf(m, ej);
            }
            float ds = 0.f;
            for (int c0 = 0; c0 < dg; c0 += 64) {
                int j = c0 + lane, cnt = min(64, dg - c0);
                int   eid = (j < dg) ? edge_list[beg + j] : 0;
                int   sj  = (j < dg) ? src[eid] : 0;
                float exj = 0.f;
                if (j < dg) {
                    float a = s1[sj] + s2d + tc * edge_d[eid];
                    float e2 = (a > 0.f) ? a : 0.01f * a;
                    exj = __expf(e2 - m);
                }
                ds += exj;
                for (int i = 0; i < cnt; ++i) {
                    int   s_i  = __shfl(sj, i);
                    float ex_i = __shfl(exj, i);
                    acc += ex_i * z[(size_t)s_i * OUT_D + lane];
                }
            }
            #pragma unroll
            for (int off = 32; off > 0; off >>= 1) ds += __shfl_xor(ds, off);
            den = ds;
        }
    }
    float inv = (den > 0.f) ? 1.f / den : 0.f;   // empty segment -> relu(z_i)
    float h = zi[(size_t)d * OUT_D + lane] + acc * inv;
    out[(size_t)d * OUT_D + lane] = fmaxf(h, 0.f);
}

extern "C" void kernel_launch(void* const* d_in, const int* in_sizes, int n_in,
                              void* d_out, int out_size, void* d_ws, size_t ws_size,
                              hipStream_t stream) {
    const float* node_feats = (const float*)d_in[0];
    const float* edge_d     = (const float*)d_in[1];
    const float* W0         = (const float*)d_in[2];
    const float* W1         = (const float*)d_in[3];
    const float* W2         = (const float*)d_in[4];
    const float* Wa         = (const float*)d_in[5];
    const int*   src        = (const int*)d_in[6];
    const int*   dst        = (const int*)d_in[7];
    float* out = (float*)d_out;

    // workspace layout (~58.2 MB)
    char* ws = (char*)d_ws;
    float* z         = (float*)ws; ws += (size_t)N_NODES * OUT_D * 4;
    float* zi        = (float*)ws; ws += (size_t)N_NODES * OUT_D * 4;
    float* s1        = (float*)ws; ws += (size_t)N_NODES * 4;
    float* s2        = (float*)ws; ws += (size_t)N_NODES * 4;
    int*   deg       = (int*)ws;   ws += (size_t)N_NODES * 4;
    int*   row_start = (int*)ws;   ws += (size_t)N_NODES * 4;
    int*   cursor    = (int*)ws;   ws += (size_t)N_NODES * 4;
    int*   partial   = (int*)ws;   ws += 4096;
    int*   edge_list = (int*)ws;   ws += (size_t)N_EDGES * 4;

    hipMemsetAsync(deg, 0, (size_t)N_NODES * 4, stream);

    histogram_kernel<<<NB_EDGES, 256, 0, stream>>>(dst, deg);

    node_proj_kernel<<<2048, 256, 0, stream>>>(node_feats, W1, W2, Wa, z, zi, s1, s2);

    scan_reduce_kernel  <<<NB_NODES, 256, 0, stream>>>(deg, partial);
    scan_partials_kernel<<<1, 512, 0, stream>>>(partial);
    scan_final_kernel   <<<NB_NODES, 256, 0, stream>>>(deg, partial, row_start, cursor);

    scatter_edges_kernel<<<NB_EDGES, 256, 0, stream>>>(dst, cursor, edge_list);

    gather_finalize_kernel<<<(N_NODES + 3) / 4, 256, 0, stream>>>(
        edge_list, row_start, deg, src, edge_d, s1, s2, W0, Wa, z, zi, out);
}

// Round 3
// 401.167 us; speedup vs baseline: 1.8267x; 1.4375x over previous
//
#include <hip/hip_runtime.h>

#define N_NODES 100000
#define N_EDGES 1250000
#define IN_D 128
#define OUT_D 64
#define NB_NODES ((N_NODES + 255) / 256)   // 391
#define NB_EDGES ((N_EDGES + 255) / 256)   // 4883

typedef __attribute__((ext_vector_type(8))) __bf16 bf16x8;
typedef __attribute__((ext_vector_type(4))) float floatx4;

// ---- K-1: pre-swizzle W = [W1^T | W2^T] (128k x 128n) into MFMA B-fragment
//           lane order, split into bf16 hi/lo. Element (nt,kc,lane,j):
//           n = nt*16 + (lane&15), k = kc*32 + (lane>>4)*8 + j.
//           flat = ((nt*4+kc)*64 + lane)*8 + j. ----
__global__ __launch_bounds__(256) void prep_w_kernel(
    const float* __restrict__ W1, const float* __restrict__ W2,
    __bf16* __restrict__ Bhi, __bf16* __restrict__ Blo)
{
    int i = blockIdx.x * 256 + threadIdx.x;
    if (i >= 16384) return;
    int j    = i & 7;
    int lane = (i >> 3) & 63;
    int blk  = i >> 9;                  // nt*4 + kc
    int nt = blk >> 2, kc = blk & 3;
    int n = nt * 16 + (lane & 15);
    int k = kc * 32 + (lane >> 4) * 8 + j;
    float w = (n < 64) ? W1[n * 128 + k] : W2[(n - 64) * 128 + k];
    __bf16 h = (__bf16)w;
    Bhi[i] = h;
    Blo[i] = (__bf16)(w - (float)h);
}

// ---- K0: node projections as split-bf16 MFMA GEMM:
//          C[100000 x 128] = X @ [W1^T | W2^T], z = C[:,0:64], zi = C[:,64:128].
//          One wave per 16 nodes. s1/s2 fused in epilogue. ----
__global__ __launch_bounds__(256) void node_proj_mfma_kernel(
    const float* __restrict__ x, const __bf16* __restrict__ Bhi,
    const __bf16* __restrict__ Blo, const float* __restrict__ Wa,
    float* __restrict__ z, float* __restrict__ zi,
    float* __restrict__ s1, float* __restrict__ s2)
{
    __shared__ __bf16 sBhi[16384];   // 32 KB, fragment-swizzled
    __shared__ __bf16 sBlo[16384];   // 32 KB
    __shared__ float  sWa[128];

    for (int i = threadIdx.x; i < 2048; i += 256) {   // 2048 uint4 per array
        ((uint4*)sBhi)[i] = ((const uint4*)Bhi)[i];
        ((uint4*)sBlo)[i] = ((const uint4*)Blo)[i];
    }
    if (threadIdx.x < 128) sWa[threadIdx.x] = Wa[threadIdx.x];
    __syncthreads();

    const int lane = threadIdx.x & 63;
    const int wave = threadIdx.x >> 6;
    const int tile = blockIdx.x * 4 + wave;           // 16-node tile
    if (tile * 16 >= N_NODES) return;                 // 100000 % 16 == 0
    const int n0 = tile * 16;

    const int m  = lane & 15;     // A row / D col
    const int kb = lane >> 4;     // k-block within chunk / D row-group

    floatx4 acc[8];
    #pragma unroll
    for (int t = 0; t < 8; ++t) acc[t] = (floatx4)(0.f);

    const float* xrow = x + (size_t)(n0 + m) * IN_D;

    #pragma unroll
    for (int kc = 0; kc < 4; ++kc) {
        // A fragment: 8 consecutive floats of this lane's row
        float4 v0 = *(const float4*)(xrow + kc * 32 + kb * 8);
        float4 v1 = *(const float4*)(xrow + kc * 32 + kb * 8 + 4);
        float xs[8] = {v0.x, v0.y, v0.z, v0.w, v1.x, v1.y, v1.z, v1.w};
        bf16x8 ahi, alo;
        #pragma unroll
        for (int j = 0; j < 8; ++j) {
            __bf16 h = (__bf16)xs[j];
            ahi[j] = h;
            alo[j] = (__bf16)(xs[j] - (float)h);
        }
        #pragma unroll
        for (int nt = 0; nt < 8; ++nt) {
            int off = ((nt * 4 + kc) * 64 + lane) * 8;
            bf16x8 bhi = *(const bf16x8*)(sBhi + off);
            bf16x8 blo = *(const bf16x8*)(sBlo + off);
            acc[nt] = __builtin_amdgcn_mfma_f32_16x16x32_bf16(ahi, bhi, acc[nt], 0, 0, 0);
            acc[nt] = __builtin_amdgcn_mfma_f32_16x16x32_bf16(ahi, blo, acc[nt], 0, 0, 0);
            acc[nt] = __builtin_amdgcn_mfma_f32_16x16x32_bf16(alo, bhi, acc[nt], 0, 0, 0);
        }
    }

    // D layout: col = lane&15 (=m), row = (lane>>4)*4 + reg (=kb*4+reg)
    #pragma unroll
    for (int nt = 0; nt < 8; ++nt) {
        float* dp = (nt < 4) ? z : zi;
        int col = (nt & 3) * 16 + m;
        #pragma unroll
        for (int reg = 0; reg < 4; ++reg) {
            int row = n0 + kb * 4 + reg;
            dp[(size_t)row * OUT_D + col] = acc[nt][reg];
        }
    }

    // s1[n] = z[n,:].Wa[0:64], s2[n] = z[n,:].Wa[64:128]; z cols live in acc[0..3]
    #pragma unroll
    for (int reg = 0; reg < 4; ++reg) {
        float p1 = 0.f, p2 = 0.f;
        #pragma unroll
        for (int nt = 0; nt < 4; ++nt) {
            float zv = acc[nt][reg];
            p1 += zv * sWa[nt * 16 + m];
            p2 += zv * sWa[64 + nt * 16 + m];
        }
        #pragma unroll
        for (int off = 8; off > 0; off >>= 1) {   // reduce over 16-lane group
            p1 += __shfl_xor(p1, off);
            p2 += __shfl_xor(p2, off);
        }
        if (m == 0) {
            int row = n0 + kb * 4 + reg;
            s1[row] = p1;
            s2[row] = p2;
        }
    }
}

// ---- K1: in-degree histogram ----
__global__ __launch_bounds__(256) void histogram_kernel(
    const int* __restrict__ dst, int* __restrict__ deg)
{
    int i = blockIdx.x * 256 + threadIdx.x;
    if (i < N_EDGES) atomicAdd(&deg[dst[i]], 1);
}

// ---- K2a/b/c: exclusive scan of deg -> row_start (and cursor copy) ----
__global__ __launch_bounds__(256) void scan_reduce_kernel(
    const int* __restrict__ deg, int* __restrict__ partial)
{
    __shared__ int s[256];
    int t = threadIdx.x, idx = blockIdx.x * 256 + t;
    s[t] = (idx < N_NODES) ? deg[idx] : 0;
    __syncthreads();
    for (int off = 128; off > 0; off >>= 1) {
        if (t < off) s[t] += s[t + off];
        __syncthreads();
    }
    if (t == 0) partial[blockIdx.x] = s[0];
}

__global__ __launch_bounds__(512) void scan_partials_kernel(int* __restrict__ partial)
{
    __shared__ int s[512];
    int t = threadIdx.x;
    int v = (t < NB_NODES) ? partial[t] : 0;
    s[t] = v;
    __syncthreads();
    for (int off = 1; off < 512; off <<= 1) {
        int add = (t >= off) ? s[t - off] : 0;
        __syncthreads();
        s[t] += add;
        __syncthreads();
    }
    if (t < NB_NODES) partial[t] = s[t] - v;   // exclusive
}

__global__ __launch_bounds__(256) void scan_final_kernel(
    const int* __restrict__ deg, const int* __restrict__ partial,
    int* __restrict__ row_start, int* __restrict__ cursor)
{
    __shared__ int s[256];
    int t = threadIdx.x, idx = blockIdx.x * 256 + t;
    int v = (idx < N_NODES) ? deg[idx] : 0;
    s[t] = v;
    __syncthreads();
    for (int off = 1; off < 256; off <<= 1) {
        int add = (t >= off) ? s[t - off] : 0;
        __syncthreads();
        s[t] += add;
        __syncthreads();
    }
    int excl = s[t] - v + partial[blockIdx.x];
    if (idx < N_NODES) { row_start[idx] = excl; cursor[idx] = excl; }
}

// ---- K3: scatter edge ids into CSR lists ----
__global__ __launch_bounds__(256) void scatter_edges_kernel(
    const int* __restrict__ dst, int* __restrict__ cursor,
    int* __restrict__ edge_list)
{
    int i = blockIdx.x * 256 + threadIdx.x;
    if (i >= N_EDGES) return;
    int pos = atomicAdd(&cursor[dst[i]], 1);
    edge_list[pos] = i;
}

// ---- K4: wave-per-dst-node gather: inline logits, softmax over the node's
//          edge list, weighted sum of z[src] rows, fused finalize. ----
__global__ __launch_bounds__(256) void gather_finalize_kernel(
    const int* __restrict__ edge_list, const int* __restrict__ row_start,
    const int* __restrict__ deg, const int* __restrict__ src,
    const float* __restrict__ edge_d, const float* __restrict__ s1,
    const float* __restrict__ s2, const float* __restrict__ W0,
    const float* __restrict__ Wa, const float* __restrict__ z,
    const float* __restrict__ zi, float* __restrict__ out)
{
    const float tc = W0[0] * Wa[2 * OUT_D];
    const int lane = threadIdx.x & 63;
    const int d = blockIdx.x * 4 + (threadIdx.x >> 6);
    if (d >= N_NODES) return;

    const int beg = row_start[d];
    const int dg  = deg[d];
    float acc = 0.f, den = 0.f;

    if (dg > 0) {
        const float s2d = s2[d];
        if (dg <= 64) {
            int   eid = (lane < dg) ? edge_list[beg + lane] : 0;
            int   sj  = (lane < dg) ? src[eid] : 0;
            float ej  = -INFINITY;
            if (lane < dg) {
                float a = s1[sj] + s2d + tc * edge_d[eid];
                ej = (a > 0.f) ? a : 0.01f * a;
            }
            float m = ej;
            #pragma unroll
            for (int off = 32; off > 0; off >>= 1) m = fmaxf(m, __shfl_xor(m, off));
            float exj = (lane < dg) ? __expf(ej - m) : 0.f;
            float ds = exj;
            #pragma unroll
            for (int off = 32; off > 0; off >>= 1) ds += __shfl_xor(ds, off);
            den = ds;
            for (int i = 0; i < dg; ++i) {
                int   s_i  = __shfl(sj, i);
                float ex_i = __shfl(exj, i);
                acc += ex_i * z[(size_t)s_i * OUT_D + lane];
            }
        } else {
            float m = -INFINITY;
            for (int c0 = 0; c0 < dg; c0 += 64) {
                int j = c0 + lane;
                float ej = -INFINITY;
                if (j < dg) {
                    int eid = edge_list[beg + j];
                    float a = s1[src[eid]] + s2d + tc * edge_d[eid];
                    ej = (a > 0.f) ? a : 0.01f * a;
                }
                #pragma unroll
                for (int off = 32; off > 0; off >>= 1) ej = fmaxf(ej, __shfl_xor(ej, off));
                m = fmaxf(m, ej);
            }
            float ds = 0.f;
            for (int c0 = 0; c0 < dg; c0 += 64) {
                int j = c0 + lane, cnt = min(64, dg - c0);
                int   eid = (j < dg) ? edge_list[beg + j] : 0;
                int   sj  = (j < dg) ? src[eid] : 0;
                float exj = 0.f;
                if (j < dg) {
                    float a = s1[sj] + s2d + tc * edge_d[eid];
                    float e2 = (a > 0.f) ? a : 0.01f * a;
                    exj = __expf(e2 - m);
                }
                ds += exj;
                for (int i = 0; i < cnt; ++i) {
                    int   s_i  = __shfl(sj, i);
                    float ex_i = __shfl(exj, i);
                    acc += ex_i * z[(size_t)s_i * OUT_D + lane];
                }
            }
            #pragma unroll
            for (int off = 32; off > 0; off >>= 1) ds += __shfl_xor(ds, off);
            den = ds;
        }
    }
    float inv = (den > 0.f) ? 1.f / den : 0.f;
    float h = zi[(size_t)d * OUT_D + lane] + acc * inv;
    out[(size_t)d * OUT_D + lane] = fmaxf(h, 0.f);
}

extern "C" void kernel_launch(void* const* d_in, const int* in_sizes, int n_in,
                              void* d_out, int out_size, void* d_ws, size_t ws_size,
                              hipStream_t stream) {
    const float* node_feats = (const float*)d_in[0];
    const float* edge_d     = (const float*)d_in[1];
    const float* W0         = (const float*)d_in[2];
    const float* W1         = (const float*)d_in[3];
    const float* W2         = (const float*)d_in[4];
    const float* Wa         = (const float*)d_in[5];
    const int*   src        = (const int*)d_in[6];
    const int*   dst        = (const int*)d_in[7];
    float* out = (float*)d_out;

    // workspace layout
    char* ws = (char*)d_ws;
    float*  z         = (float*)ws;  ws += (size_t)N_NODES * OUT_D * 4;
    float*  zi        = (float*)ws;  ws += (size_t)N_NODES * OUT_D * 4;
    float*  s1        = (float*)ws;  ws += (size_t)N_NODES * 4;
    float*  s2        = (float*)ws;  ws += (size_t)N_NODES * 4;
    int*    deg       = (int*)ws;    ws += (size_t)N_NODES * 4;
    int*    row_start = (int*)ws;    ws += (size_t)N_NODES * 4;
    int*    cursor    = (int*)ws;    ws += (size_t)N_NODES * 4;
    int*    partial   = (int*)ws;    ws += 4096;
    __bf16* Bhi       = (__bf16*)ws; ws += 16384 * 2;
    __bf16* Blo       = (__bf16*)ws; ws += 16384 * 2;
    int*    edge_list = (int*)ws;    ws += (size_t)N_EDGES * 4;

    hipMemsetAsync(deg, 0, (size_t)N_NODES * 4, stream);

    prep_w_kernel<<<64, 256, 0, stream>>>(W1, W2, Bhi, Blo);

    histogram_kernel<<<NB_EDGES, 256, 0, stream>>>(dst, deg);

    node_proj_mfma_kernel<<<(6250 + 3) / 4, 256, 0, stream>>>(
        node_feats, Bhi, Blo, Wa, z, zi, s1, s2);

    scan_reduce_kernel  <<<NB_NODES, 256, 0, stream>>>(deg, partial);
    scan_partials_kernel<<<1, 512, 0, stream>>>(partial);
    scan_final_kernel   <<<NB_NODES, 256, 0, stream>>>(deg, partial, row_start, cursor);

    scatter_edges_kernel<<<NB_EDGES, 256, 0, stream>>>(dst, cursor, edge_list);

    gather_finalize_kernel<<<(N_NODES + 3) / 4, 256, 0, stream>>>(
        edge_list, row_start, deg, src, edge_d, s1, s2, W0, Wa, z, zi, out);
}

// Round 4
// 355.537 us; speedup vs baseline: 2.0611x; 1.1283x over previous
//
#include <hip/hip_runtime.h>

#define N_NODES 100000
#define N_EDGES 1250000
#define IN_D 128
#define OUT_D 64
#define NB_NODES ((N_NODES + 255) / 256)   // 391
#define NB_EDGES ((N_EDGES + 255) / 256)   // 4883

typedef __attribute__((ext_vector_type(8))) __bf16 bf16x8;
typedef __attribute__((ext_vector_type(4))) float floatx4;

__device__ __forceinline__ float bf2f(unsigned short u) {
    return __uint_as_float(((unsigned)u) << 16);
}

// ---- K0a: fused prep: blocks [0,64) swizzle W into MFMA B-fragment order
//           (split bf16 hi/lo); blocks [64,...) build the in-degree histogram.
__global__ __launch_bounds__(256) void prep_hist_kernel(
    const float* __restrict__ W1, const float* __restrict__ W2,
    __bf16* __restrict__ Bhi, __bf16* __restrict__ Blo,
    const int* __restrict__ dst, int* __restrict__ deg)
{
    if (blockIdx.x < 64) {
        int i = blockIdx.x * 256 + threadIdx.x;   // < 16384
        int j    = i & 7;
        int lane = (i >> 3) & 63;
        int blk  = i >> 9;                  // nt*4 + kc
        int nt = blk >> 2, kc = blk & 3;
        int n = nt * 16 + (lane & 15);
        int k = kc * 32 + (lane >> 4) * 8 + j;
        float w = (n < 64) ? W1[n * 128 + k] : W2[(n - 64) * 128 + k];
        __bf16 h = (__bf16)w;
        Bhi[i] = h;
        Blo[i] = (__bf16)(w - (float)h);
    } else {
        int i = (blockIdx.x - 64) * 256 + threadIdx.x;
        if (i < N_EDGES) atomicAdd(&deg[dst[i]], 1);
    }
}

// ---- K0b: node projections as split-bf16 MFMA GEMM:
//          C[100000 x 128] = X @ [W1^T | W2^T]; z stored as bf16 (gather-only
//          consumer), zi as fp32; s1/s2 from fp32 accs in epilogue. ----
__global__ __launch_bounds__(256) void node_proj_mfma_kernel(
    const float* __restrict__ x, const __bf16* __restrict__ Bhi,
    const __bf16* __restrict__ Blo, const float* __restrict__ Wa,
    unsigned short* __restrict__ zb, float* __restrict__ zi,
    float* __restrict__ s1, float* __restrict__ s2)
{
    __shared__ __bf16 sBhi[16384];   // 32 KB, fragment-swizzled
    __shared__ __bf16 sBlo[16384];   // 32 KB
    __shared__ float  sWa[128];

    for (int i = threadIdx.x; i < 2048; i += 256) {
        ((uint4*)sBhi)[i] = ((const uint4*)Bhi)[i];
        ((uint4*)sBlo)[i] = ((const uint4*)Blo)[i];
    }
    if (threadIdx.x < 128) sWa[threadIdx.x] = Wa[threadIdx.x];
    __syncthreads();

    const int lane = threadIdx.x & 63;
    const int wave = threadIdx.x >> 6;
    const int tile = blockIdx.x * 4 + wave;           // 16-node tile
    if (tile * 16 >= N_NODES) return;                 // 100000 % 16 == 0
    const int n0 = tile * 16;

    const int m  = lane & 15;     // A row / D col
    const int kb = lane >> 4;     // k-block within chunk / D row-group

    floatx4 acc[8];
    #pragma unroll
    for (int t = 0; t < 8; ++t) acc[t] = (floatx4)(0.f);

    const float* xrow = x + (size_t)(n0 + m) * IN_D;

    #pragma unroll
    for (int kc = 0; kc < 4; ++kc) {
        float4 v0 = *(const float4*)(xrow + kc * 32 + kb * 8);
        float4 v1 = *(const float4*)(xrow + kc * 32 + kb * 8 + 4);
        float xs[8] = {v0.x, v0.y, v0.z, v0.w, v1.x, v1.y, v1.z, v1.w};
        bf16x8 ahi, alo;
        #pragma unroll
        for (int j = 0; j < 8; ++j) {
            __bf16 h = (__bf16)xs[j];
            ahi[j] = h;
            alo[j] = (__bf16)(xs[j] - (float)h);
        }
        #pragma unroll
        for (int nt = 0; nt < 8; ++nt) {
            int off = ((nt * 4 + kc) * 64 + lane) * 8;
            bf16x8 bhi = *(const bf16x8*)(sBhi + off);
            bf16x8 blo = *(const bf16x8*)(sBlo + off);
            acc[nt] = __builtin_amdgcn_mfma_f32_16x16x32_bf16(ahi, bhi, acc[nt], 0, 0, 0);
            acc[nt] = __builtin_amdgcn_mfma_f32_16x16x32_bf16(ahi, blo, acc[nt], 0, 0, 0);
            acc[nt] = __builtin_amdgcn_mfma_f32_16x16x32_bf16(alo, bhi, acc[nt], 0, 0, 0);
        }
    }

    // D layout: col = lane&15 (=m), row = (lane>>4)*4 + reg (=kb*4+reg)
    #pragma unroll
    for (int nt = 0; nt < 8; ++nt) {
        int col = (nt & 3) * 16 + m;
        #pragma unroll
        for (int reg = 0; reg < 4; ++reg) {
            int row = n0 + kb * 4 + reg;
            if (nt < 4) {
                __bf16 h = (__bf16)acc[nt][reg];
                zb[(size_t)row * OUT_D + col] = *(unsigned short*)&h;
            } else {
                zi[(size_t)row * OUT_D + col] = acc[nt][reg];
            }
        }
    }

    // s1[n] = z[n,:].Wa[0:64], s2[n] = z[n,:].Wa[64:128]  (fp32 accs)
    #pragma unroll
    for (int reg = 0; reg < 4; ++reg) {
        float p1 = 0.f, p2 = 0.f;
        #pragma unroll
        for (int nt = 0; nt < 4; ++nt) {
            float zv = acc[nt][reg];
            p1 += zv * sWa[nt * 16 + m];
            p2 += zv * sWa[64 + nt * 16 + m];
        }
        #pragma unroll
        for (int off = 8; off > 0; off >>= 1) {
            p1 += __shfl_xor(p1, off);
            p2 += __shfl_xor(p2, off);
        }
        if (m == 0) {
            int row = n0 + kb * 4 + reg;
            s1[row] = p1;
            s2[row] = p2;
        }
    }
}

// ---- K2a/b/c: exclusive scan of deg -> row_start (and cursor copy) ----
__global__ __launch_bounds__(256) void scan_reduce_kernel(
    const int* __restrict__ deg, int* __restrict__ partial)
{
    __shared__ int s[256];
    int t = threadIdx.x, idx = blockIdx.x * 256 + t;
    s[t] = (idx < N_NODES) ? deg[idx] : 0;
    __syncthreads();
    for (int off = 128; off > 0; off >>= 1) {
        if (t < off) s[t] += s[t + off];
        __syncthreads();
    }
    if (t == 0) partial[blockIdx.x] = s[0];
}

__global__ __launch_bounds__(512) void scan_partials_kernel(int* __restrict__ partial)
{
    __shared__ int s[512];
    int t = threadIdx.x;
    int v = (t < NB_NODES) ? partial[t] : 0;
    s[t] = v;
    __syncthreads();
    for (int off = 1; off < 512; off <<= 1) {
        int add = (t >= off) ? s[t - off] : 0;
        __syncthreads();
        s[t] += add;
        __syncthreads();
    }
    if (t < NB_NODES) partial[t] = s[t] - v;   // exclusive
}

__global__ __launch_bounds__(256) void scan_final_kernel(
    const int* __restrict__ deg, const int* __restrict__ partial,
    int* __restrict__ row_start, int* __restrict__ cursor)
{
    __shared__ int s[256];
    int t = threadIdx.x, idx = blockIdx.x * 256 + t;
    int v = (idx < N_NODES) ? deg[idx] : 0;
    s[t] = v;
    __syncthreads();
    for (int off = 1; off < 256; off <<= 1) {
        int add = (t >= off) ? s[t - off] : 0;
        __syncthreads();
        s[t] += add;
        __syncthreads();
    }
    int excl = s[t] - v + partial[blockIdx.x];
    if (idx < N_NODES) { row_start[idx] = excl; cursor[idx] = excl; }
}

// ---- K3: scatter edge ids into CSR lists ----
__global__ __launch_bounds__(256) void scatter_edges_kernel(
    const int* __restrict__ dst, int* __restrict__ cursor,
    int* __restrict__ edge_list)
{
    int i = blockIdx.x * 256 + threadIdx.x;
    if (i >= N_EDGES) return;
    int pos = atomicAdd(&cursor[dst[i]], 1);
    edge_list[pos] = i;
}

// ---- K4: wave-per-dst-node gather: inline logits, softmax, bf16 z weighted
//          sum (4-way unrolled for loads-in-flight), fused finalize. ----
__global__ __launch_bounds__(256) void gather_finalize_kernel(
    const int* __restrict__ edge_list, const int* __restrict__ row_start,
    const int* __restrict__ deg, const int* __restrict__ src,
    const float* __restrict__ edge_d, const float* __restrict__ s1,
    const float* __restrict__ s2, const float* __restrict__ W0,
    const float* __restrict__ Wa, const unsigned short* __restrict__ zb,
    const float* __restrict__ zi, float* __restrict__ out)
{
    const float tc = W0[0] * Wa[2 * OUT_D];
    const int lane = threadIdx.x & 63;
    const int d = blockIdx.x * 4 + (threadIdx.x >> 6);
    if (d >= N_NODES) return;

    const int beg = row_start[d];
    const int dg  = deg[d];
    float acc = 0.f, den = 0.f;

    if (dg > 0) {
        const float s2d = s2[d];
        if (dg <= 64) {
            // single-chunk fast path: each lane owns one edge
            int   eid = (lane < dg) ? edge_list[beg + lane] : 0;
            int   sj  = (lane < dg) ? src[eid] : 0;
            float ej  = -INFINITY;
            if (lane < dg) {
                float a = s1[sj] + s2d + tc * edge_d[eid];
                ej = (a > 0.f) ? a : 0.01f * a;
            }
            float m = ej;
            #pragma unroll
            for (int off = 32; off > 0; off >>= 1) m = fmaxf(m, __shfl_xor(m, off));
            float exj = (lane < dg) ? __expf(ej - m) : 0.f;
            float ds = exj;
            #pragma unroll
            for (int off = 32; off > 0; off >>= 1) ds += __shfl_xor(ds, off);
            den = ds;

            int i = 0;
            for (; i + 4 <= dg; i += 4) {
                int   sa = __shfl(sj, i),     sb = __shfl(sj, i + 1);
                int   sc = __shfl(sj, i + 2), sd = __shfl(sj, i + 3);
                float ea = __shfl(exj, i),     eb = __shfl(exj, i + 1);
                float ec = __shfl(exj, i + 2), ed = __shfl(exj, i + 3);
                unsigned short za = zb[(size_t)sa * OUT_D + lane];
                unsigned short zb_ = zb[(size_t)sb * OUT_D + lane];
                unsigned short zc = zb[(size_t)sc * OUT_D + lane];
                unsigned short zd = zb[(size_t)sd * OUT_D + lane];
                acc += ea * bf2f(za) + eb * bf2f(zb_) + ec * bf2f(zc) + ed * bf2f(zd);
            }
            for (; i < dg; ++i) {
                int   s_i  = __shfl(sj, i);
                float ex_i = __shfl(exj, i);
                acc += ex_i * bf2f(zb[(size_t)s_i * OUT_D + lane]);
            }
        } else {
            // general chunked two-pass path
            float m = -INFINITY;
            for (int c0 = 0; c0 < dg; c0 += 64) {
                int j = c0 + lane;
                float ej = -INFINITY;
                if (j < dg) {
                    int eid = edge_list[beg + j];
                    float a = s1[src[eid]] + s2d + tc * edge_d[eid];
                    ej = (a > 0.f) ? a : 0.01f * a;
                }
                #pragma unroll
                for (int off = 32; off > 0; off >>= 1) ej = fmaxf(ej, __shfl_xor(ej, off));
                m = fmaxf(m, ej);
            }
            float ds = 0.f;
            for (int c0 = 0; c0 < dg; c0 += 64) {
                int j = c0 + lane, cnt = min(64, dg - c0);
                int   eid = (j < dg) ? edge_list[beg + j] : 0;
                int   sj  = (j < dg) ? src[eid] : 0;
                float exj = 0.f;
                if (j < dg) {
                    float a = s1[sj] + s2d + tc * edge_d[eid];
                    float e2 = (a > 0.f) ? a : 0.01f * a;
                    exj = __expf(e2 - m);
                }
                ds += exj;
                int i = 0;
                for (; i + 4 <= cnt; i += 4) {
                    int   sa = __shfl(sj, i),     sb = __shfl(sj, i + 1);
                    int   sc = __shfl(sj, i + 2), sd = __shfl(sj, i + 3);
                    float ea = __shfl(exj, i),     eb = __shfl(exj, i + 1);
                    float ec = __shfl(exj, i + 2), ed = __shfl(exj, i + 3);
                    unsigned short za = zb[(size_t)sa * OUT_D + lane];
                    unsigned short zb_ = zb[(size_t)sb * OUT_D + lane];
                    unsigned short zc = zb[(size_t)sc * OUT_D + lane];
                    unsigned short zd = zb[(size_t)sd * OUT_D + lane];
                    acc += ea * bf2f(za) + eb * bf2f(zb_) + ec * bf2f(zc) + ed * bf2f(zd);
                }
                for (; i < cnt; ++i) {
                    int   s_i  = __shfl(sj, i);
                    float ex_i = __shfl(exj, i);
                    acc += ex_i * bf2f(zb[(size_t)s_i * OUT_D + lane]);
                }
            }
            #pragma unroll
            for (int off = 32; off > 0; off >>= 1) ds += __shfl_xor(ds, off);
            den = ds;
        }
    }
    float inv = (den > 0.f) ? 1.f / den : 0.f;   // empty segment -> relu(z_i)
    float h = zi[(size_t)d * OUT_D + lane] + acc * inv;
    out[(size_t)d * OUT_D + lane] = fmaxf(h, 0.f);
}

extern "C" void kernel_launch(void* const* d_in, const int* in_sizes, int n_in,
                              void* d_out, int out_size, void* d_ws, size_t ws_size,
                              hipStream_t stream) {
    const float* node_feats = (const float*)d_in[0];
    const float* edge_d     = (const float*)d_in[1];
    const float* W0         = (const float*)d_in[2];
    const float* W1         = (const float*)d_in[3];
    const float* W2         = (const float*)d_in[4];
    const float* Wa         = (const float*)d_in[5];
    const int*   src        = (const int*)d_in[6];
    const int*   dst        = (const int*)d_in[7];
    float* out = (float*)d_out;

    // workspace layout
    char* ws = (char*)d_ws;
    unsigned short* zbuf = (unsigned short*)ws; ws += (size_t)N_NODES * OUT_D * 2;
    float*  zi        = (float*)ws;  ws += (size_t)N_NODES * OUT_D * 4;
    float*  s1        = (float*)ws;  ws += (size_t)N_NODES * 4;
    float*  s2        = (float*)ws;  ws += (size_t)N_NODES * 4;
    int*    deg       = (int*)ws;    ws += (size_t)N_NODES * 4;
    int*    row_start = (int*)ws;    ws += (size_t)N_NODES * 4;
    int*    cursor    = (int*)ws;    ws += (size_t)N_NODES * 4;
    int*    partial   = (int*)ws;    ws += 4096;
    __bf16* Bhi       = (__bf16*)ws; ws += 16384 * 2;
    __bf16* Blo       = (__bf16*)ws; ws += 16384 * 2;
    int*    edge_list = (int*)ws;    ws += (size_t)N_EDGES * 4;

    hipMemsetAsync(deg, 0, (size_t)N_NODES * 4, stream);

    prep_hist_kernel<<<64 + NB_EDGES, 256, 0, stream>>>(W1, W2, Bhi, Blo, dst, deg);

    node_proj_mfma_kernel<<<(6250 + 3) / 4, 256, 0, stream>>>(
        node_feats, Bhi, Blo, Wa, zbuf, zi, s1, s2);

    scan_reduce_kernel  <<<NB_NODES, 256, 0, stream>>>(deg, partial);
    scan_partials_kernel<<<1, 512, 0, stream>>>(partial);
    scan_final_kernel   <<<NB_NODES, 256, 0, stream>>>(deg, partial, row_start, cursor);

    scatter_edges_kernel<<<NB_EDGES, 256, 0, stream>>>(dst, cursor, edge_list);

    gather_finalize_kernel<<<(N_NODES + 3) / 4, 256, 0, stream>>>(
        edge_list, row_start, deg, src, edge_d, s1, s2, W0, Wa, zbuf, zi, out);
}

// Round 5
// 310.025 us; speedup vs baseline: 2.3637x; 1.1468x over previous
//
#include <hip/hip_runtime.h>

#define N_NODES 100000
#define N_EDGES 1250000
#define IN_D 128
#define OUT_D 64
#define NB_EDGES ((N_EDGES + 255) / 256)   // 4883
#define SEG_CNT  (8 * N_NODES)             // sharded segment counters
#define SEG_PAD  800768                    // 391 * 2048 (scan-friendly pad)
#define NB_SCAN  391

typedef __attribute__((ext_vector_type(8))) __bf16 bf16x8;
typedef __attribute__((ext_vector_type(4))) float floatx4;

__device__ __forceinline__ float bf2f(unsigned short u) {
    return __uint_as_float(((unsigned)u) << 16);
}

// ---- K0a: fused prep: blocks [0,64) swizzle W into MFMA B-fragment order
//           (split bf16 hi/lo); blocks [64,...) sharded in-degree histogram.
//           shard(edge block b) = b & 7  (64 % 8 == 0 keeps phase aligned). ----
__global__ __launch_bounds__(256) void prep_hist_kernel(
    const float* __restrict__ W1, const float* __restrict__ W2,
    __bf16* __restrict__ Bhi, __bf16* __restrict__ Blo,
    const int* __restrict__ dst, int* __restrict__ deg)
{
    if (blockIdx.x < 64) {
        int i = blockIdx.x * 256 + threadIdx.x;   // < 16384
        int j    = i & 7;
        int lane = (i >> 3) & 63;
        int blk  = i >> 9;                  // nt*4 + kc
        int nt = blk >> 2, kc = blk & 3;
        int n = nt * 16 + (lane & 15);
        int k = kc * 32 + (lane >> 4) * 8 + j;
        float w = (n < 64) ? W1[n * 128 + k] : W2[(n - 64) * 128 + k];
        __bf16 h = (__bf16)w;
        Bhi[i] = h;
        Blo[i] = (__bf16)(w - (float)h);
    } else {
        int b = blockIdx.x - 64;
        int i = b * 256 + threadIdx.x;
        if (i < N_EDGES) {
            int shard = b & 7;
            atomicAdd(&deg[shard * N_NODES + dst[i]], 1);
        }
    }
}

// ---- K0b: node projections as split-bf16 MFMA GEMM (unchanged from R4) ----
__global__ __launch_bounds__(256) void node_proj_mfma_kernel(
    const float* __restrict__ x, const __bf16* __restrict__ Bhi,
    const __bf16* __restrict__ Blo, const float* __restrict__ Wa,
    unsigned short* __restrict__ zb, float* __restrict__ zi,
    float* __restrict__ s1, float* __restrict__ s2)
{
    __shared__ __bf16 sBhi[16384];
    __shared__ __bf16 sBlo[16384];
    __shared__ float  sWa[128];

    for (int i = threadIdx.x; i < 2048; i += 256) {
        ((uint4*)sBhi)[i] = ((const uint4*)Bhi)[i];
        ((uint4*)sBlo)[i] = ((const uint4*)Blo)[i];
    }
    if (threadIdx.x < 128) sWa[threadIdx.x] = Wa[threadIdx.x];
    __syncthreads();

    const int lane = threadIdx.x & 63;
    const int wave = threadIdx.x >> 6;
    const int tile = blockIdx.x * 4 + wave;
    if (tile * 16 >= N_NODES) return;
    const int n0 = tile * 16;

    const int m  = lane & 15;
    const int kb = lane >> 4;

    floatx4 acc[8];
    #pragma unroll
    for (int t = 0; t < 8; ++t) acc[t] = (floatx4)(0.f);

    const float* xrow = x + (size_t)(n0 + m) * IN_D;

    #pragma unroll
    for (int kc = 0; kc < 4; ++kc) {
        float4 v0 = *(const float4*)(xrow + kc * 32 + kb * 8);
        float4 v1 = *(const float4*)(xrow + kc * 32 + kb * 8 + 4);
        float xs[8] = {v0.x, v0.y, v0.z, v0.w, v1.x, v1.y, v1.z, v1.w};
        bf16x8 ahi, alo;
        #pragma unroll
        for (int j = 0; j < 8; ++j) {
            __bf16 h = (__bf16)xs[j];
            ahi[j] = h;
            alo[j] = (__bf16)(xs[j] - (float)h);
        }
        #pragma unroll
        for (int nt = 0; nt < 8; ++nt) {
            int off = ((nt * 4 + kc) * 64 + lane) * 8;
            bf16x8 bhi = *(const bf16x8*)(sBhi + off);
            bf16x8 blo = *(const bf16x8*)(sBlo + off);
            acc[nt] = __builtin_amdgcn_mfma_f32_16x16x32_bf16(ahi, bhi, acc[nt], 0, 0, 0);
            acc[nt] = __builtin_amdgcn_mfma_f32_16x16x32_bf16(ahi, blo, acc[nt], 0, 0, 0);
            acc[nt] = __builtin_amdgcn_mfma_f32_16x16x32_bf16(alo, bhi, acc[nt], 0, 0, 0);
        }
    }

    #pragma unroll
    for (int nt = 0; nt < 8; ++nt) {
        int col = (nt & 3) * 16 + m;
        #pragma unroll
        for (int reg = 0; reg < 4; ++reg) {
            int row = n0 + kb * 4 + reg;
            if (nt < 4) {
                __bf16 h = (__bf16)acc[nt][reg];
                zb[(size_t)row * OUT_D + col] = *(unsigned short*)&h;
            } else {
                zi[(size_t)row * OUT_D + col] = acc[nt][reg];
            }
        }
    }

    #pragma unroll
    for (int reg = 0; reg < 4; ++reg) {
        float p1 = 0.f, p2 = 0.f;
        #pragma unroll
        for (int nt = 0; nt < 4; ++nt) {
            float zv = acc[nt][reg];
            p1 += zv * sWa[nt * 16 + m];
            p2 += zv * sWa[64 + nt * 16 + m];
        }
        #pragma unroll
        for (int off = 8; off > 0; off >>= 1) {
            p1 += __shfl_xor(p1, off);
            p2 += __shfl_xor(p2, off);
        }
        if (m == 0) {
            int row = n0 + kb * 4 + reg;
            s1[row] = p1;
            s2[row] = p2;
        }
    }
}

// ---- K2: 3-stage exclusive scan over SEG_PAD counters (8 per thread) ----
__global__ __launch_bounds__(256) void scan_reduce_kernel(
    const int* __restrict__ deg, int* __restrict__ partial)
{
    int t = threadIdx.x;
    int base = (blockIdx.x * 256 + t) * 8;
    int4 a = *(const int4*)(deg + base);
    int4 b = *(const int4*)(deg + base + 4);
    int s = a.x + a.y + a.z + a.w + b.x + b.y + b.z + b.w;
    __shared__ int sm[256];
    sm[t] = s;
    __syncthreads();
    for (int off = 128; off > 0; off >>= 1) {
        if (t < off) sm[t] += sm[t + off];
        __syncthreads();
    }
    if (t == 0) partial[blockIdx.x] = sm[0];
}

__global__ __launch_bounds__(512) void scan_partials_kernel(int* __restrict__ partial)
{
    __shared__ int s[512];
    int t = threadIdx.x;
    int v = (t < NB_SCAN) ? partial[t] : 0;
    s[t] = v;
    __syncthreads();
    for (int off = 1; off < 512; off <<= 1) {
        int add = (t >= off) ? s[t - off] : 0;
        __syncthreads();
        s[t] += add;
        __syncthreads();
    }
    if (t < NB_SCAN) partial[t] = s[t] - v;   // exclusive
}

__global__ __launch_bounds__(256) void scan_final_kernel(
    const int* __restrict__ deg, const int* __restrict__ partial,
    int* __restrict__ row)
{
    int t = threadIdx.x;
    int base = (blockIdx.x * 256 + t) * 8;
    int4 a = *(const int4*)(deg + base);
    int4 b = *(const int4*)(deg + base + 4);
    int v[8] = {a.x, a.y, a.z, a.w, b.x, b.y, b.z, b.w};
    int s = 0;
    #pragma unroll
    for (int j = 0; j < 8; ++j) s += v[j];
    __shared__ int sm[256];
    sm[t] = s;
    __syncthreads();
    for (int off = 1; off < 256; off <<= 1) {
        int add = (t >= off) ? sm[t - off] : 0;
        __syncthreads();
        sm[t] += add;
        __syncthreads();
    }
    int run = partial[blockIdx.x] + sm[t] - s;   // exclusive thread offset
    #pragma unroll
    for (int j = 0; j < 8; ++j) { row[base + j] = run; run += v[j]; }
}

// ---- K3: sharded payload scatter. Atomics on row[] turn starts into ends.
//          payload = {src, s1[src] + tc*edge_d}  (8 B, XCD-local region). ----
__global__ __launch_bounds__(256) void scatter_payload_kernel(
    const int* __restrict__ dst, const int* __restrict__ src,
    const float* __restrict__ edge_d, const float* __restrict__ s1,
    const float* __restrict__ W0, const float* __restrict__ Wa,
    int* __restrict__ row, uint2* __restrict__ payload)
{
    int i = blockIdx.x * 256 + threadIdx.x;
    if (i >= N_EDGES) return;
    const float tc = W0[0] * Wa[2 * OUT_D];
    int shard = blockIdx.x & 7;
    int d  = dst[i];
    int sj = src[i];
    float apart = s1[sj] + tc * edge_d[i];
    int pos = atomicAdd(&row[shard * N_NODES + d], 1);
    payload[pos] = make_uint2((unsigned)sj, __float_as_uint(apart));
}

// ---- K4: wave-per-dst-node gather over 8 shard sub-segments:
//          logits from payload, softmax, bf16 z weighted sum, finalize. ----
__global__ __launch_bounds__(256) void gather_finalize_kernel(
    const int* __restrict__ row_end, const int* __restrict__ deg,
    const uint2* __restrict__ payload, const float* __restrict__ s2,
    const unsigned short* __restrict__ zb, const float* __restrict__ zi,
    float* __restrict__ out)
{
    const int lane = threadIdx.x & 63;
    const int d = blockIdx.x * 4 + (threadIdx.x >> 6);
    if (d >= N_NODES) return;

    // lanes 0..7 hold their shard's (start, len)
    int st8 = 0, ln8 = 0;
    if (lane < 8) {
        int idx = lane * N_NODES + d;
        int en = row_end[idx];
        ln8 = deg[idx];
        st8 = en - ln8;
    }
    int cum = ln8;                       // 8-wide inclusive prefix (lanes 0..7)
    #pragma unroll
    for (int off = 1; off < 8; off <<= 1) {
        int t = __shfl_up(cum, off);
        if (lane >= off && lane < 8) cum += t;
    }
    const int dg = __shfl(cum, 7);
    const int cumex = cum - ln8;

    float acc = 0.f, den = 0.f;

    if (dg > 0) {
        const float s2d = s2[d];
        if (dg <= 64) {
            // rank(lane) -> payload index via shard search
            int base = 0;
            #pragma unroll
            for (int s = 0; s < 8; ++s) {
                int ce = __shfl(cumex, s);
                int bs = __shfl(st8, s);
                if (lane >= ce) base = bs - ce;
            }
            uint2 p = (lane < dg) ? payload[base + lane] : make_uint2(0u, 0u);
            int   sj = (int)p.x;
            float ej = -INFINITY;
            if (lane < dg) {
                float a = __uint_as_float(p.y) + s2d;
                ej = (a > 0.f) ? a : 0.01f * a;
            }
            float m = ej;
            #pragma unroll
            for (int off = 32; off > 0; off >>= 1) m = fmaxf(m, __shfl_xor(m, off));
            float exj = (lane < dg) ? __expf(ej - m) : 0.f;
            float ds = exj;
            #pragma unroll
            for (int off = 32; off > 0; off >>= 1) ds += __shfl_xor(ds, off);
            den = ds;

            int i = 0;
            for (; i + 4 <= dg; i += 4) {
                int   sa = __shfl(sj, i),     sb = __shfl(sj, i + 1);
                int   sc = __shfl(sj, i + 2), sd = __shfl(sj, i + 3);
                float ea = __shfl(exj, i),     eb = __shfl(exj, i + 1);
                float ec = __shfl(exj, i + 2), ed = __shfl(exj, i + 3);
                unsigned short za = zb[(size_t)sa * OUT_D + lane];
                unsigned short zb_ = zb[(size_t)sb * OUT_D + lane];
                unsigned short zc = zb[(size_t)sc * OUT_D + lane];
                unsigned short zd = zb[(size_t)sd * OUT_D + lane];
                acc += ea * bf2f(za) + eb * bf2f(zb_) + ec * bf2f(zc) + ed * bf2f(zd);
            }
            for (; i < dg; ++i) {
                int   s_i  = __shfl(sj, i);
                float ex_i = __shfl(exj, i);
                acc += ex_i * bf2f(zb[(size_t)s_i * OUT_D + lane]);
            }
        } else {
            // general chunked two-pass path
            float m = -INFINITY;
            for (int c0 = 0; c0 < dg; c0 += 64) {
                int j = c0 + lane;
                int base = 0;
                #pragma unroll
                for (int s = 0; s < 8; ++s) {
                    int ce = __shfl(cumex, s);
                    int bs = __shfl(st8, s);
                    if (j >= ce) base = bs - ce;
                }
                float ej = -INFINITY;
                if (j < dg) {
                    uint2 p = payload[base + j];
                    float a = __uint_as_float(p.y) + s2d;
                    ej = (a > 0.f) ? a : 0.01f * a;
                }
                #pragma unroll
                for (int off = 32; off > 0; off >>= 1) ej = fmaxf(ej, __shfl_xor(ej, off));
                m = fmaxf(m, ej);
            }
            float ds = 0.f;
            for (int c0 = 0; c0 < dg; c0 += 64) {
                int j = c0 + lane, cnt = min(64, dg - c0);
                int base = 0;
                #pragma unroll
                for (int s = 0; s < 8; ++s) {
                    int ce = __shfl(cumex, s);
                    int bs = __shfl(st8, s);
                    if (j >= ce) base = bs - ce;
                }
                int sj = 0;
                float exj = 0.f;
                if (j < dg) {
                    uint2 p = payload[base + j];
                    sj = (int)p.x;
                    float a = __uint_as_float(p.y) + s2d;
                    float e2 = (a > 0.f) ? a : 0.01f * a;
                    exj = __expf(e2 - m);
                }
                ds += exj;
                int i = 0;
                for (; i + 4 <= cnt; i += 4) {
                    int   sa = __shfl(sj, i),     sb = __shfl(sj, i + 1);
                    int   sc = __shfl(sj, i + 2), sd = __shfl(sj, i + 3);
                    float ea = __shfl(exj, i),     eb = __shfl(exj, i + 1);
                    float ec = __shfl(exj, i + 2), ed = __shfl(exj, i + 3);
                    unsigned short za = zb[(size_t)sa * OUT_D + lane];
                    unsigned short zb_ = zb[(size_t)sb * OUT_D + lane];
                    unsigned short zc = zb[(size_t)sc * OUT_D + lane];
                    unsigned short zd = zb[(size_t)sd * OUT_D + lane];
                    acc += ea * bf2f(za) + eb * bf2f(zb_) + ec * bf2f(zc) + ed * bf2f(zd);
                }
                for (; i < cnt; ++i) {
                    int   s_i  = __shfl(sj, i);
                    float ex_i = __shfl(exj, i);
                    acc += ex_i * bf2f(zb[(size_t)s_i * OUT_D + lane]);
                }
            }
            #pragma unroll
            for (int off = 32; off > 0; off >>= 1) ds += __shfl_xor(ds, off);
            den = ds;
        }
    }
    float inv = (den > 0.f) ? 1.f / den : 0.f;   // empty segment -> relu(z_i)
    float h = zi[(size_t)d * OUT_D + lane] + acc * inv;
    out[(size_t)d * OUT_D + lane] = fmaxf(h, 0.f);
}

extern "C" void kernel_launch(void* const* d_in, const int* in_sizes, int n_in,
                              void* d_out, int out_size, void* d_ws, size_t ws_size,
                              hipStream_t stream) {
    const float* node_feats = (const float*)d_in[0];
    const float* edge_d     = (const float*)d_in[1];
    const float* W0         = (const float*)d_in[2];
    const float* W1         = (const float*)d_in[3];
    const float* W2         = (const float*)d_in[4];
    const float* Wa         = (const float*)d_in[5];
    const int*   src        = (const int*)d_in[6];
    const int*   dst        = (const int*)d_in[7];
    float* out = (float*)d_out;

    // workspace layout (~55.7 MB); payload first for 8 B alignment
    char* ws = (char*)d_ws;
    uint2*  payload = (uint2*)ws;  ws += (size_t)N_EDGES * 8;
    float*  zi      = (float*)ws;  ws += (size_t)N_NODES * OUT_D * 4;
    float*  s1      = (float*)ws;  ws += (size_t)N_NODES * 4;
    float*  s2      = (float*)ws;  ws += (size_t)N_NODES * 4;
    int*    deg     = (int*)ws;    ws += (size_t)SEG_PAD * 4;
    int*    row     = (int*)ws;    ws += (size_t)SEG_PAD * 4;
    int*    partial = (int*)ws;    ws += 4096;
    __bf16* Bhi     = (__bf16*)ws; ws += 16384 * 2;
    __bf16* Blo     = (__bf16*)ws; ws += 16384 * 2;
    unsigned short* zbuf = (unsigned short*)ws; ws += (size_t)N_NODES * OUT_D * 2;

    hipMemsetAsync(deg, 0, (size_t)SEG_PAD * 4, stream);

    prep_hist_kernel<<<64 + NB_EDGES, 256, 0, stream>>>(W1, W2, Bhi, Blo, dst, deg);

    node_proj_mfma_kernel<<<(6250 + 3) / 4, 256, 0, stream>>>(
        node_feats, Bhi, Blo, Wa, zbuf, zi, s1, s2);

    scan_reduce_kernel  <<<NB_SCAN, 256, 0, stream>>>(deg, partial);
    scan_partials_kernel<<<1, 512, 0, stream>>>(partial);
    scan_final_kernel   <<<NB_SCAN, 256, 0, stream>>>(deg, partial, row);

    scatter_payload_kernel<<<NB_EDGES, 256, 0, stream>>>(
        dst, src, edge_d, s1, W0, Wa, row, payload);

    gather_finalize_kernel<<<(N_NODES + 3) / 4, 256, 0, stream>>>(
        row, deg, payload, s2, zbuf, zi, out);
}

// Round 6
// 292.928 us; speedup vs baseline: 2.5017x; 1.0584x over previous
//
#include <hip/hip_runtime.h>

#define N_NODES 100000
#define N_EDGES 1250000
#define IN_D 128
#define OUT_D 64
#define NB_EDGES ((N_EDGES + 255) / 256)   // 4883
#define SEG_PAD  800768                    // 391 * 2048 (scan-friendly pad)
#define NB_SCAN  391

typedef __attribute__((ext_vector_type(8))) __bf16 bf16x8;
typedef __attribute__((ext_vector_type(4))) float floatx4;

// ---- K0a: fused prep: blocks [0,64) swizzle W=[W1^T|W2^T] into MFMA
//           B-fragment order (single bf16); blocks [64,..) sharded histogram.
__global__ __launch_bounds__(256) void prep_hist_kernel(
    const float* __restrict__ W1, const float* __restrict__ W2,
    __bf16* __restrict__ B,
    const int* __restrict__ dst, int* __restrict__ deg)
{
    if (blockIdx.x < 64) {
        int i = blockIdx.x * 256 + threadIdx.x;   // < 16384
        int j    = i & 7;
        int lane = (i >> 3) & 63;
        int blk  = i >> 9;                  // nt*4 + kc
        int nt = blk >> 2, kc = blk & 3;
        int n = nt * 16 + (lane & 15);
        int k = kc * 32 + (lane >> 4) * 8 + j;
        float w = (n < 64) ? W1[n * 128 + k] : W2[(n - 64) * 128 + k];
        B[i] = (__bf16)w;
    } else {
        int b = blockIdx.x - 64;
        int i = b * 256 + threadIdx.x;
        if (i < N_EDGES) {
            int shard = b & 7;
            atomicAdd(&deg[shard * N_NODES + dst[i]], 1);
        }
    }
}

// ---- K0b: node projections as split-x bf16 MFMA GEMM (W single bf16):
//          C = (x_hi + x_lo) @ [W1^T | W2^T]; z,zi stored bf16; s1/s2 fp32. ----
__global__ __launch_bounds__(256) void node_proj_mfma_kernel(
    const float* __restrict__ x, const __bf16* __restrict__ B,
    const float* __restrict__ Wa,
    unsigned short* __restrict__ zb, unsigned short* __restrict__ zib,
    float* __restrict__ s1, float* __restrict__ s2)
{
    __shared__ __bf16 sB[16384];     // 32 KB, fragment-swizzled
    __shared__ float  sWa[128];

    for (int i = threadIdx.x; i < 2048; i += 256)
        ((uint4*)sB)[i] = ((const uint4*)B)[i];
    if (threadIdx.x < 128) sWa[threadIdx.x] = Wa[threadIdx.x];
    __syncthreads();

    const int lane = threadIdx.x & 63;
    const int wave = threadIdx.x >> 6;
    const int tile = blockIdx.x * 4 + wave;
    if (tile * 16 >= N_NODES) return;          // 100000 % 16 == 0
    const int n0 = tile * 16;

    const int m  = lane & 15;
    const int kb = lane >> 4;

    floatx4 acc[8];
    #pragma unroll
    for (int t = 0; t < 8; ++t) acc[t] = (floatx4)(0.f);

    const float* xrow = x + (size_t)(n0 + m) * IN_D;

    #pragma unroll
    for (int kc = 0; kc < 4; ++kc) {
        float4 v0 = *(const float4*)(xrow + kc * 32 + kb * 8);
        float4 v1 = *(const float4*)(xrow + kc * 32 + kb * 8 + 4);
        float xs[8] = {v0.x, v0.y, v0.z, v0.w, v1.x, v1.y, v1.z, v1.w};
        bf16x8 ahi, alo;
        #pragma unroll
        for (int j = 0; j < 8; ++j) {
            __bf16 h = (__bf16)xs[j];
            ahi[j] = h;
            alo[j] = (__bf16)(xs[j] - (float)h);
        }
        #pragma unroll
        for (int nt = 0; nt < 8; ++nt) {
            int off = ((nt * 4 + kc) * 64 + lane) * 8;
            bf16x8 b = *(const bf16x8*)(sB + off);
            acc[nt] = __builtin_amdgcn_mfma_f32_16x16x32_bf16(ahi, b, acc[nt], 0, 0, 0);
            acc[nt] = __builtin_amdgcn_mfma_f32_16x16x32_bf16(alo, b, acc[nt], 0, 0, 0);
        }
    }

    // D layout: col = lane&15 (=m), row = kb*4 + reg
    #pragma unroll
    for (int nt = 0; nt < 8; ++nt) {
        int col = (nt & 3) * 16 + m;
        unsigned short* dp = (nt < 4) ? zb : zib;
        #pragma unroll
        for (int reg = 0; reg < 4; ++reg) {
            int row = n0 + kb * 4 + reg;
            __bf16 h = (__bf16)acc[nt][reg];
            dp[(size_t)row * OUT_D + col] = *(unsigned short*)&h;
        }
    }

    // s1[n] = z[n,:].Wa[0:64], s2[n] = z[n,:].Wa[64:128]  (fp32 accs)
    #pragma unroll
    for (int reg = 0; reg < 4; ++reg) {
        float p1 = 0.f, p2 = 0.f;
        #pragma unroll
        for (int nt = 0; nt < 4; ++nt) {
            float zv = acc[nt][reg];
            p1 += zv * sWa[nt * 16 + m];
            p2 += zv * sWa[64 + nt * 16 + m];
        }
        #pragma unroll
        for (int off = 8; off > 0; off >>= 1) {
            p1 += __shfl_xor(p1, off);
            p2 += __shfl_xor(p2, off);
        }
        if (m == 0) {
            int row = n0 + kb * 4 + reg;
            s1[row] = p1;
            s2[row] = p2;
        }
    }
}

// ---- K2: 3-stage exclusive scan over SEG_PAD counters (8 per thread) ----
__global__ __launch_bounds__(256) void scan_reduce_kernel(
    const int* __restrict__ deg, int* __restrict__ partial)
{
    int t = threadIdx.x;
    int base = (blockIdx.x * 256 + t) * 8;
    int4 a = *(const int4*)(deg + base);
    int4 b = *(const int4*)(deg + base + 4);
    int s = a.x + a.y + a.z + a.w + b.x + b.y + b.z + b.w;
    __shared__ int sm[256];
    sm[t] = s;
    __syncthreads();
    for (int off = 128; off > 0; off >>= 1) {
        if (t < off) sm[t] += sm[t + off];
        __syncthreads();
    }
    if (t == 0) partial[blockIdx.x] = sm[0];
}

__global__ __launch_bounds__(512) void scan_partials_kernel(int* __restrict__ partial)
{
    __shared__ int s[512];
    int t = threadIdx.x;
    int v = (t < NB_SCAN) ? partial[t] : 0;
    s[t] = v;
    __syncthreads();
    for (int off = 1; off < 512; off <<= 1) {
        int add = (t >= off) ? s[t - off] : 0;
        __syncthreads();
        s[t] += add;
        __syncthreads();
    }
    if (t < NB_SCAN) partial[t] = s[t] - v;   // exclusive
}

__global__ __launch_bounds__(256) void scan_final_kernel(
    const int* __restrict__ deg, const int* __restrict__ partial,
    int* __restrict__ row)
{
    int t = threadIdx.x;
    int base = (blockIdx.x * 256 + t) * 8;
    int4 a = *(const int4*)(deg + base);
    int4 b = *(const int4*)(deg + base + 4);
    int v[8] = {a.x, a.y, a.z, a.w, b.x, b.y, b.z, b.w};
    int s = 0;
    #pragma unroll
    for (int j = 0; j < 8; ++j) s += v[j];
    __shared__ int sm[256];
    sm[t] = s;
    __syncthreads();
    for (int off = 1; off < 256; off <<= 1) {
        int add = (t >= off) ? sm[t - off] : 0;
        __syncthreads();
        sm[t] += add;
        __syncthreads();
    }
    int run = partial[blockIdx.x] + sm[t] - s;   // exclusive thread offset
    #pragma unroll
    for (int j = 0; j < 8; ++j) { row[base + j] = run; run += v[j]; }
}

// ---- K3: sharded payload scatter. Atomics on row[] turn starts into ends.
//          payload = {src, s1[src] + tc*edge_d}  (8 B, XCD-local region). ----
__global__ __launch_bounds__(256) void scatter_payload_kernel(
    const int* __restrict__ dst, const int* __restrict__ src,
    const float* __restrict__ edge_d, const float* __restrict__ s1,
    const float* __restrict__ W0, const float* __restrict__ Wa,
    int* __restrict__ row, uint2* __restrict__ payload)
{
    int i = blockIdx.x * 256 + threadIdx.x;
    if (i >= N_EDGES) return;
    const float tc = W0[0] * Wa[2 * OUT_D];
    int shard = blockIdx.x & 7;
    int d  = dst[i];
    int sj = src[i];
    float apart = s1[sj] + tc * edge_d[i];
    int pos = atomicAdd(&row[shard * N_NODES + d], 1);
    payload[pos] = make_uint2((unsigned)sj, __float_as_uint(apart));
}

// ---- K4: wave-per-dst-node gather over 8 shard sub-segments.
//          No segment max (logits are O(10); fp32 exp can't overflow).
//          Weighted sum: lane = (edge_slot e = lane>>3, chunk c = lane&7);
//          each lane loads 16 B (8 bf16 feats) of its edge's z row ->
//          one VMEM instruction covers 8 edges. ----
__global__ __launch_bounds__(256) void gather_finalize_kernel(
    const int* __restrict__ row_end, const int* __restrict__ deg,
    const uint2* __restrict__ payload, const float* __restrict__ s2,
    const unsigned short* __restrict__ zb, const unsigned short* __restrict__ zib,
    float* __restrict__ out)
{
    const int lane = threadIdx.x & 63;
    const int d = blockIdx.x * 4 + (threadIdx.x >> 6);
    if (d >= N_NODES) return;

    // lanes 0..7 hold their shard's (start, len)
    int st8 = 0, ln8 = 0;
    if (lane < 8) {
        int idx = lane * N_NODES + d;
        int en = row_end[idx];
        ln8 = deg[idx];
        st8 = en - ln8;
    }
    int cum = ln8;                       // 8-wide inclusive prefix (lanes 0..7)
    #pragma unroll
    for (int off = 1; off < 8; off <<= 1) {
        int t = __shfl_up(cum, off);
        if (lane >= off && lane < 8) cum += t;
    }
    const int dg = __shfl(cum, 7);
    const int cumex = cum - ln8;

    float acc8[8];
    #pragma unroll
    for (int k = 0; k < 8; ++k) acc8[k] = 0.f;
    float den = 0.f;

    if (dg > 0) {
        const float s2d = s2[d];
        const int eIdx = lane >> 3;       // edge slot within 8-group
        const int c    = lane & 7;        // feature chunk

        for (int c0 = 0; c0 < dg; c0 += 64) {
            int j = c0 + lane;
            // rank j -> payload index via shard select chain
            int base = 0;
            #pragma unroll
            for (int s = 0; s < 8; ++s) {
                int ce = __shfl(cumex, s);
                int bs = __shfl(st8, s);
                if (j >= ce) base = bs - ce;
            }
            int sj = 0;
            float ex = 0.f;
            if (j < dg) {
                uint2 p = payload[base + j];
                sj = (int)p.x;
                float a = __uint_as_float(p.y) + s2d;
                float e = (a > 0.f) ? a : 0.01f * a;
                ex = __expf(e);
            }
            den += ex;

            int cnt = min(64, dg - c0);
            for (int g = 0; g < cnt; g += 8) {
                int sl = g + eIdx;
                int   s_t = __shfl(sj, sl & 63);
                float e_t = __shfl(ex, sl & 63);
                bool valid = (sl < cnt);
                int   s_e  = valid ? s_t : 0;
                float ex_e = valid ? e_t : 0.f;
                uint4 zv = *(const uint4*)(zb + (size_t)s_e * OUT_D + c * 8);
                acc8[0] += ex_e * __uint_as_float(zv.x << 16);
                acc8[1] += ex_e * __uint_as_float(zv.x & 0xFFFF0000u);
                acc8[2] += ex_e * __uint_as_float(zv.y << 16);
                acc8[3] += ex_e * __uint_as_float(zv.y & 0xFFFF0000u);
                acc8[4] += ex_e * __uint_as_float(zv.z << 16);
                acc8[5] += ex_e * __uint_as_float(zv.z & 0xFFFF0000u);
                acc8[6] += ex_e * __uint_as_float(zv.w << 16);
                acc8[7] += ex_e * __uint_as_float(zv.w & 0xFFFF0000u);
            }
        }
        #pragma unroll
        for (int off = 32; off > 0; off >>= 1) den += __shfl_xor(den, off);
        // reduce acc8 across the 8 edge slots (lane bits 3..5)
        #pragma unroll
        for (int off = 8; off < 64; off <<= 1) {
            #pragma unroll
            for (int k = 0; k < 8; ++k) acc8[k] += __shfl_xor(acc8[k], off);
        }
    }

    // epilogue: lanes 0..7 write features c*8 .. c*8+7
    if (lane < 8) {
        float inv = (den > 0.f) ? 1.f / den : 0.f;   // empty segment -> relu(zi)
        uint4 zv = *(const uint4*)(zib + (size_t)d * OUT_D + lane * 8);
        float4 o0, o1;
        o0.x = fmaxf(__uint_as_float(zv.x << 16)          + acc8[0] * inv, 0.f);
        o0.y = fmaxf(__uint_as_float(zv.x & 0xFFFF0000u)  + acc8[1] * inv, 0.f);
        o0.z = fmaxf(__uint_as_float(zv.y << 16)          + acc8[2] * inv, 0.f);
        o0.w = fmaxf(__uint_as_float(zv.y & 0xFFFF0000u)  + acc8[3] * inv, 0.f);
        o1.x = fmaxf(__uint_as_float(zv.z << 16)          + acc8[4] * inv, 0.f);
        o1.y = fmaxf(__uint_as_float(zv.z & 0xFFFF0000u)  + acc8[5] * inv, 0.f);
        o1.z = fmaxf(__uint_as_float(zv.w << 16)          + acc8[6] * inv, 0.f);
        o1.w = fmaxf(__uint_as_float(zv.w & 0xFFFF0000u)  + acc8[7] * inv, 0.f);
        *(float4*)(out + (size_t)d * OUT_D + lane * 8)     = o0;
        *(float4*)(out + (size_t)d * OUT_D + lane * 8 + 4) = o1;
    }
}

extern "C" void kernel_launch(void* const* d_in, const int* in_sizes, int n_in,
                              void* d_out, int out_size, void* d_ws, size_t ws_size,
                              hipStream_t stream) {
    const float* node_feats = (const float*)d_in[0];
    const float* edge_d     = (const float*)d_in[1];
    const float* W0         = (const float*)d_in[2];
    const float* W1         = (const float*)d_in[3];
    const float* W2         = (const float*)d_in[4];
    const float* Wa         = (const float*)d_in[5];
    const int*   src        = (const int*)d_in[6];
    const int*   dst        = (const int*)d_in[7];
    float* out = (float*)d_out;

    // workspace layout (~43 MB), all sections 16 B aligned
    char* ws = (char*)d_ws;
    uint2*  payload = (uint2*)ws;  ws += (size_t)N_EDGES * 8;
    unsigned short* zbuf = (unsigned short*)ws; ws += (size_t)N_NODES * OUT_D * 2;
    unsigned short* zib  = (unsigned short*)ws; ws += (size_t)N_NODES * OUT_D * 2;
    float*  s1      = (float*)ws;  ws += (size_t)N_NODES * 4;
    float*  s2      = (float*)ws;  ws += (size_t)N_NODES * 4;
    int*    deg     = (int*)ws;    ws += (size_t)SEG_PAD * 4;
    int*    row     = (int*)ws;    ws += (size_t)SEG_PAD * 4;
    int*    partial = (int*)ws;    ws += 4096;
    __bf16* B       = (__bf16*)ws; ws += 16384 * 2;

    hipMemsetAsync(deg, 0, (size_t)SEG_PAD * 4, stream);

    prep_hist_kernel<<<64 + NB_EDGES, 256, 0, stream>>>(W1, W2, B, dst, deg);

    node_proj_mfma_kernel<<<(6250 + 3) / 4, 256, 0, stream>>>(
        node_feats, B, Wa, zbuf, zib, s1, s2);

    scan_reduce_kernel  <<<NB_SCAN, 256, 0, stream>>>(deg, partial);
    scan_partials_kernel<<<1, 512, 0, stream>>>(partial);
    scan_final_kernel   <<<NB_SCAN, 256, 0, stream>>>(deg, partial, row);

    scatter_payload_kernel<<<NB_EDGES, 256, 0, stream>>>(
        dst, src, edge_d, s1, W0, Wa, row, payload);

    gather_finalize_kernel<<<(N_NODES + 3) / 4, 256, 0, stream>>>(
        row, deg, payload, s2, zbuf, zib, out);
}

// Round 7
// 271.717 us; speedup vs baseline: 2.6969x; 1.0781x over previous
//
#include <hip/hip_runtime.h>

#define N_NODES 100000
#define N_EDGES 1250000
#define IN_D 128
#define OUT_D 64
#define NB_EDGES ((N_EDGES + 255) / 256)   // 4883
#define SEG_PAD  800768                    // 391 * 2048 (scan-friendly pad)
#define NB_SCAN  391

typedef __attribute__((ext_vector_type(8))) __bf16 bf16x8;
typedef __attribute__((ext_vector_type(4))) float floatx4;

__device__ __forceinline__ float2 up2(unsigned u) {   // 2 bf16 -> 2 f32
    return make_float2(__uint_as_float(u << 16),
                       __uint_as_float(u & 0xFFFF0000u));
}

// ---- K0a: fused prep: blocks [0,64) swizzle W=[W1^T|W2^T] into MFMA
//           B-fragment order (single bf16); blocks [64,..) sharded histogram.
__global__ __launch_bounds__(256) void prep_hist_kernel(
    const float* __restrict__ W1, const float* __restrict__ W2,
    __bf16* __restrict__ B,
    const int* __restrict__ dst, int* __restrict__ deg)
{
    if (blockIdx.x < 64) {
        int i = blockIdx.x * 256 + threadIdx.x;   // < 16384
        int j    = i & 7;
        int lane = (i >> 3) & 63;
        int blk  = i >> 9;                  // nt*4 + kc
        int nt = blk >> 2, kc = blk & 3;
        int n = nt * 16 + (lane & 15);
        int k = kc * 32 + (lane >> 4) * 8 + j;
        float w = (n < 64) ? W1[n * 128 + k] : W2[(n - 64) * 128 + k];
        B[i] = (__bf16)w;
    } else {
        int b = blockIdx.x - 64;
        int i = b * 256 + threadIdx.x;
        if (i < N_EDGES) {
            int shard = b & 7;
            atomicAdd(&deg[shard * N_NODES + dst[i]], 1);
        }
    }
}

// ---- K0b: node projections as split-x bf16 MFMA GEMM (W single bf16):
//          C = (x_hi + x_lo) @ [W1^T | W2^T]; z,zi stored bf16; s1/s2 fp32. ----
__global__ __launch_bounds__(256) void node_proj_mfma_kernel(
    const float* __restrict__ x, const __bf16* __restrict__ B,
    const float* __restrict__ Wa,
    unsigned short* __restrict__ zb, unsigned short* __restrict__ zib,
    float* __restrict__ s1, float* __restrict__ s2)
{
    __shared__ __bf16 sB[16384];     // 32 KB, fragment-swizzled
    __shared__ float  sWa[128];

    for (int i = threadIdx.x; i < 2048; i += 256)
        ((uint4*)sB)[i] = ((const uint4*)B)[i];
    if (threadIdx.x < 128) sWa[threadIdx.x] = Wa[threadIdx.x];
    __syncthreads();

    const int lane = threadIdx.x & 63;
    const int wave = threadIdx.x >> 6;
    const int tile = blockIdx.x * 4 + wave;
    if (tile * 16 >= N_NODES) return;          // 100000 % 16 == 0
    const int n0 = tile * 16;

    const int m  = lane & 15;
    const int kb = lane >> 4;

    floatx4 acc[8];
    #pragma unroll
    for (int t = 0; t < 8; ++t) acc[t] = (floatx4)(0.f);

    const float* xrow = x + (size_t)(n0 + m) * IN_D;

    #pragma unroll
    for (int kc = 0; kc < 4; ++kc) {
        float4 v0 = *(const float4*)(xrow + kc * 32 + kb * 8);
        float4 v1 = *(const float4*)(xrow + kc * 32 + kb * 8 + 4);
        float xs[8] = {v0.x, v0.y, v0.z, v0.w, v1.x, v1.y, v1.z, v1.w};
        bf16x8 ahi, alo;
        #pragma unroll
        for (int j = 0; j < 8; ++j) {
            __bf16 h = (__bf16)xs[j];
            ahi[j] = h;
            alo[j] = (__bf16)(xs[j] - (float)h);
        }
        #pragma unroll
        for (int nt = 0; nt < 8; ++nt) {
            int off = ((nt * 4 + kc) * 64 + lane) * 8;
            bf16x8 b = *(const bf16x8*)(sB + off);
            acc[nt] = __builtin_amdgcn_mfma_f32_16x16x32_bf16(ahi, b, acc[nt], 0, 0, 0);
            acc[nt] = __builtin_amdgcn_mfma_f32_16x16x32_bf16(alo, b, acc[nt], 0, 0, 0);
        }
    }

    // D layout: col = lane&15 (=m), row = kb*4 + reg
    #pragma unroll
    for (int nt = 0; nt < 8; ++nt) {
        int col = (nt & 3) * 16 + m;
        unsigned short* dp = (nt < 4) ? zb : zib;
        #pragma unroll
        for (int reg = 0; reg < 4; ++reg) {
            int row = n0 + kb * 4 + reg;
            __bf16 h = (__bf16)acc[nt][reg];
            dp[(size_t)row * OUT_D + col] = *(unsigned short*)&h;
        }
    }

    // s1[n] = z[n,:].Wa[0:64], s2[n] = z[n,:].Wa[64:128]  (fp32 accs)
    #pragma unroll
    for (int reg = 0; reg < 4; ++reg) {
        float p1 = 0.f, p2 = 0.f;
        #pragma unroll
        for (int nt = 0; nt < 4; ++nt) {
            float zv = acc[nt][reg];
            p1 += zv * sWa[nt * 16 + m];
            p2 += zv * sWa[64 + nt * 16 + m];
        }
        #pragma unroll
        for (int off = 8; off > 0; off >>= 1) {
            p1 += __shfl_xor(p1, off);
            p2 += __shfl_xor(p2, off);
        }
        if (m == 0) {
            int row = n0 + kb * 4 + reg;
            s1[row] = p1;
            s2[row] = p2;
        }
    }
}

// ---- K2: 3-stage exclusive scan over SEG_PAD counters (8 per thread) ----
__global__ __launch_bounds__(256) void scan_reduce_kernel(
    const int* __restrict__ deg, int* __restrict__ partial)
{
    int t = threadIdx.x;
    int base = (blockIdx.x * 256 + t) * 8;
    int4 a = *(const int4*)(deg + base);
    int4 b = *(const int4*)(deg + base + 4);
    int s = a.x + a.y + a.z + a.w + b.x + b.y + b.z + b.w;
    __shared__ int sm[256];
    sm[t] = s;
    __syncthreads();
    for (int off = 128; off > 0; off >>= 1) {
        if (t < off) sm[t] += sm[t + off];
        __syncthreads();
    }
    if (t == 0) partial[blockIdx.x] = sm[0];
}

__global__ __launch_bounds__(512) void scan_partials_kernel(int* __restrict__ partial)
{
    __shared__ int s[512];
    int t = threadIdx.x;
    int v = (t < NB_SCAN) ? partial[t] : 0;
    s[t] = v;
    __syncthreads();
    for (int off = 1; off < 512; off <<= 1) {
        int add = (t >= off) ? s[t - off] : 0;
        __syncthreads();
        s[t] += add;
        __syncthreads();
    }
    if (t < NB_SCAN) partial[t] = s[t] - v;   // exclusive
}

__global__ __launch_bounds__(256) void scan_final_kernel(
    const int* __restrict__ deg, const int* __restrict__ partial,
    int* __restrict__ row)
{
    int t = threadIdx.x;
    int base = (blockIdx.x * 256 + t) * 8;
    int4 a = *(const int4*)(deg + base);
    int4 b = *(const int4*)(deg + base + 4);
    int v[8] = {a.x, a.y, a.z, a.w, b.x, b.y, b.z, b.w};
    int s = 0;
    #pragma unroll
    for (int j = 0; j < 8; ++j) s += v[j];
    __shared__ int sm[256];
    sm[t] = s;
    __syncthreads();
    for (int off = 1; off < 256; off <<= 1) {
        int add = (t >= off) ? sm[t - off] : 0;
        __syncthreads();
        sm[t] += add;
        __syncthreads();
    }
    int run = partial[blockIdx.x] + sm[t] - s;   // exclusive thread offset
    #pragma unroll
    for (int j = 0; j < 8; ++j) { row[base + j] = run; run += v[j]; }
}

// ---- K3: sharded payload scatter. Atomics on row[] turn starts into ends.
//          payload = {src, s1[src] + tc*edge_d}  (8 B, XCD-local region). ----
__global__ __launch_bounds__(256) void scatter_payload_kernel(
    const int* __restrict__ dst, const int* __restrict__ src,
    const float* __restrict__ edge_d, const float* __restrict__ s1,
    const float* __restrict__ W0, const float* __restrict__ Wa,
    int* __restrict__ row, uint2* __restrict__ payload)
{
    int i = blockIdx.x * 256 + threadIdx.x;
    if (i >= N_EDGES) return;
    const float tc = W0[0] * Wa[2 * OUT_D];
    int shard = blockIdx.x & 7;
    int d  = dst[i];
    int sj = src[i];
    float apart = s1[sj] + tc * edge_d[i];
    int pos = atomicAdd(&row[shard * N_NODES + d], 1);
    payload[pos] = make_uint2((unsigned)sj, __float_as_uint(apart));
}

// ---- K4: TWO nodes per wave (32 lanes each). Phase B: 8 shards x 4 slots
//          per node -> payload idx = shardStart + o + slot (no select chain);
//          ballot-compact (src, exp) into a 32-entry LDS queue per node.
//          Phase C: 4 edge slots x 8 chunks; (src,ex) via broadcast ds_read.
//          No segment max (logits O(10), fp32 exp safe). ----
__global__ __launch_bounds__(256) void gather_finalize_kernel(
    const int* __restrict__ row_end, const int* __restrict__ deg,
    const uint2* __restrict__ payload, const float* __restrict__ s2,
    const unsigned short* __restrict__ zb, const unsigned short* __restrict__ zib,
    float* __restrict__ out)
{
    __shared__ uint2 buf[8][32];               // per node-slot (src, ex-bits)

    const int lane = threadIdx.x & 63;
    const int wave = threadIdx.x >> 6;
    const int half = lane >> 5;                // node within wave
    const int lh   = lane & 31;                // lane within half
    const int nodeSlot = wave * 2 + half;      // 0..7
    const int d = blockIdx.x * 8 + nodeSlot;   // 100000 % 8 == 0

    // meta: lanes lh<8 of each half load shard (len, start)
    int ln = 0, st = 0;
    if (lh < 8) {
        int idx = lh * N_NODES + d;
        int en = row_end[idx];
        ln = deg[idx];
        st = en - ln;
    }
    // phase-B mapping: shard = lh>>2, slot = lh&3
    const int metaSrc = (lane & 32) + (lh >> 2);
    const int ln_me = __shfl(ln, metaSrc);
    const int st_me = __shfl(st, metaSrc);
    const int slotB = lh & 3;

    const float s2d = s2[d];
    const int eC = lh >> 3;                    // phase-C edge slot (0..3)
    const int c  = lh & 7;                     // feature chunk (8 bf16 = 16 B)
    const unsigned long long halfbit = 1ull << lane;

    float den = 0.f;
    float2 a0 = make_float2(0.f, 0.f), a1 = a0, a2 = a0, a3 = a0;

    int o = 0;
    for (;;) {
        bool valid = (o + slotB) < ln_me;
        unsigned long long bal = __ballot(valid);
        if (!bal) break;
        unsigned hm = (unsigned)(bal >> (lane & 32));
        int cnt = __popc(hm);                  // this iter's entries, my half

        int gaddr = valid ? (st_me + o + slotB) : 0;
        uint2 p = payload[gaddr];
        float a = __uint_as_float(p.y) + s2d;
        float e = (a > 0.f) ? a : 0.01f * a;
        float ex = valid ? __expf(e) : 0.f;
        den += ex;
        if (valid) {
            int pos = __popc(hm & (unsigned)(((1ull << lh) - 1)));
            buf[nodeSlot][pos] = make_uint2(p.x, __float_as_uint(ex));
        }
        // same-wave LDS write->read: hardware-ordered, compiler adds lgkmcnt

        for (int g = 0; g * 4 < cnt; ++g) {
            int j = g * 4 + eC;
            uint2 pe = buf[nodeSlot][(j < cnt) ? j : 0];
            float exe = (j < cnt) ? __uint_as_float(pe.y) : 0.f;
            uint4 zv = *(const uint4*)(zb + (size_t)pe.x * OUT_D + c * 8);
            float2 w0 = up2(zv.x), w1 = up2(zv.y), w2 = up2(zv.z), w3 = up2(zv.w);
            a0.x = fmaf(exe, w0.x, a0.x); a0.y = fmaf(exe, w0.y, a0.y);
            a1.x = fmaf(exe, w1.x, a1.x); a1.y = fmaf(exe, w1.y, a1.y);
            a2.x = fmaf(exe, w2.x, a2.x); a2.y = fmaf(exe, w2.y, a2.y);
            a3.x = fmaf(exe, w3.x, a3.x); a3.y = fmaf(exe, w3.y, a3.y);
        }
        o += 4;
    }

    // reductions within each half: den over 32 lanes, acc over 4 edge slots
    #pragma unroll
    for (int off = 16; off > 0; off >>= 1) den += __shfl_xor(den, off);
    #pragma unroll
    for (int off = 8; off <= 16; off <<= 1) {
        a0.x += __shfl_xor(a0.x, off); a0.y += __shfl_xor(a0.y, off);
        a1.x += __shfl_xor(a1.x, off); a1.y += __shfl_xor(a1.y, off);
        a2.x += __shfl_xor(a2.x, off); a2.y += __shfl_xor(a2.y, off);
        a3.x += __shfl_xor(a3.x, off); a3.y += __shfl_xor(a3.y, off);
    }

    // epilogue: lanes with eC==0 (lh 0..7) write chunk c = lh (8 feats)
    if (lh < 8) {
        float inv = (den > 0.f) ? 1.f / den : 0.f;   // empty -> relu(zi)
        uint4 zv = *(const uint4*)(zib + (size_t)d * OUT_D + lh * 8);
        float2 w0 = up2(zv.x), w1 = up2(zv.y), w2 = up2(zv.z), w3 = up2(zv.w);
        float4 o0, o1;
        o0.x = fmaxf(w0.x + a0.x * inv, 0.f);
        o0.y = fmaxf(w0.y + a0.y * inv, 0.f);
        o0.z = fmaxf(w1.x + a1.x * inv, 0.f);
        o0.w = fmaxf(w1.y + a1.y * inv, 0.f);
        o1.x = fmaxf(w2.x + a2.x * inv, 0.f);
        o1.y = fmaxf(w2.y + a2.y * inv, 0.f);
        o1.z = fmaxf(w3.x + a3.x * inv, 0.f);
        o1.w = fmaxf(w3.y + a3.y * inv, 0.f);
        *(float4*)(out + (size_t)d * OUT_D + lh * 8)     = o0;
        *(float4*)(out + (size_t)d * OUT_D + lh * 8 + 4) = o1;
    }
}

extern "C" void kernel_launch(void* const* d_in, const int* in_sizes, int n_in,
                              void* d_out, int out_size, void* d_ws, size_t ws_size,
                              hipStream_t stream) {
    const float* node_feats = (const float*)d_in[0];
    const float* edge_d     = (const float*)d_in[1];
    const float* W0         = (const float*)d_in[2];
    const float* W1         = (const float*)d_in[3];
    const float* W2         = (const float*)d_in[4];
    const float* Wa         = (const float*)d_in[5];
    const int*   src        = (const int*)d_in[6];
    const int*   dst        = (const int*)d_in[7];
    float* out = (float*)d_out;

    // workspace layout (~43 MB), all sections 16 B aligned
    char* ws = (char*)d_ws;
    uint2*  payload = (uint2*)ws;  ws += (size_t)N_EDGES * 8;
    unsigned short* zbuf = (unsigned short*)ws; ws += (size_t)N_NODES * OUT_D * 2;
    unsigned short* zib  = (unsigned short*)ws; ws += (size_t)N_NODES * OUT_D * 2;
    float*  s1      = (float*)ws;  ws += (size_t)N_NODES * 4;
    float*  s2      = (float*)ws;  ws += (size_t)N_NODES * 4;
    int*    deg     = (int*)ws;    ws += (size_t)SEG_PAD * 4;
    int*    row     = (int*)ws;    ws += (size_t)SEG_PAD * 4;
    int*    partial = (int*)ws;    ws += 4096;
    __bf16* B       = (__bf16*)ws; ws += 16384 * 2;

    hipMemsetAsync(deg, 0, (size_t)SEG_PAD * 4, stream);

    prep_hist_kernel<<<64 + NB_EDGES, 256, 0, stream>>>(W1, W2, B, dst, deg);

    node_proj_mfma_kernel<<<(6250 + 3) / 4, 256, 0, stream>>>(
        node_feats, B, Wa, zbuf, zib, s1, s2);

    scan_reduce_kernel  <<<NB_SCAN, 256, 0, stream>>>(deg, partial);
    scan_partials_kernel<<<1, 512, 0, stream>>>(partial);
    scan_final_kernel   <<<NB_SCAN, 256, 0, stream>>>(deg, partial, row);

    scatter_payload_kernel<<<NB_EDGES, 256, 0, stream>>>(
        dst, src, edge_d, s1, W0, Wa, row, payload);

    gather_finalize_kernel<<<N_NODES / 8, 256, 0, stream>>>(
        row, deg, payload, s2, zbuf, zib, out);
}

// Round 8
// 232.921 us; speedup vs baseline: 3.1462x; 1.1666x over previous
//
#include <hip/hip_runtime.h>

#define N_NODES 100000
#define N_EDGES 1250000
#define IN_D 128
#define OUT_D 64
#define BSHIFT 9                                  // 512 nodes per bucket
#define NBUCK  196                                // ceil(100000/512)
#define EPB    8192                               // edges per fat block
#define NBLK_E ((N_EDGES + EPB - 1) / EPB)        // 153

typedef __attribute__((ext_vector_type(8))) __bf16 bf16x8;
typedef __attribute__((ext_vector_type(4))) float floatx4;

__device__ __forceinline__ float2 up2(unsigned u) {   // 2 bf16 -> 2 f32
    return make_float2(__uint_as_float(u << 16),
                       __uint_as_float(u & 0xFFFF0000u));
}

// ---- K0a: blocks [0,64): swizzle W=[W1^T|W2^T] into MFMA B-fragment order
//           (bf16). blocks [64,64+153): LDS-aggregated bucket histogram. ----
__global__ __launch_bounds__(256) void prep_hist_kernel(
    const float* __restrict__ W1, const float* __restrict__ W2,
    __bf16* __restrict__ B, const int* __restrict__ dst,
    int* __restrict__ gh)
{
    __shared__ int h[NBUCK];
    if (blockIdx.x < 64) {
        int i = blockIdx.x * 256 + threadIdx.x;   // < 16384
        int j    = i & 7;
        int lane = (i >> 3) & 63;
        int blk  = i >> 9;                  // nt*4 + kc
        int nt = blk >> 2, kc = blk & 3;
        int n = nt * 16 + (lane & 15);
        int k = kc * 32 + (lane >> 4) * 8 + j;
        float w = (n < 64) ? W1[n * 128 + k] : W2[(n - 64) * 128 + k];
        B[i] = (__bf16)w;
    } else {
        for (int i = threadIdx.x; i < NBUCK; i += 256) h[i] = 0;
        __syncthreads();
        int base = (blockIdx.x - 64) * EPB;
        #pragma unroll 4
        for (int k = 0; k < EPB / 256; ++k) {
            int i = base + k * 256 + threadIdx.x;
            if (i < N_EDGES) atomicAdd(&h[dst[i] >> BSHIFT], 1);
        }
        __syncthreads();
        for (int i = threadIdx.x; i < NBUCK; i += 256)
            if (h[i]) atomicAdd(&gh[i], h[i]);
    }
}

// ---- K0b: node projections as split-x bf16 MFMA GEMM (W single bf16):
//          C = (x_hi + x_lo) @ [W1^T | W2^T]; z,zi stored bf16; s1/s2 fp32. ----
__global__ __launch_bounds__(256) void node_proj_mfma_kernel(
    const float* __restrict__ x, const __bf16* __restrict__ B,
    const float* __restrict__ Wa,
    unsigned short* __restrict__ zb, unsigned short* __restrict__ zib,
    float* __restrict__ s1, float* __restrict__ s2)
{
    __shared__ __bf16 sB[16384];     // 32 KB, fragment-swizzled
    __shared__ float  sWa[128];

    for (int i = threadIdx.x; i < 2048; i += 256)
        ((uint4*)sB)[i] = ((const uint4*)B)[i];
    if (threadIdx.x < 128) sWa[threadIdx.x] = Wa[threadIdx.x];
    __syncthreads();

    const int lane = threadIdx.x & 63;
    const int wave = threadIdx.x >> 6;
    const int tile = blockIdx.x * 4 + wave;
    if (tile * 16 >= N_NODES) return;          // 100000 % 16 == 0
    const int n0 = tile * 16;

    const int m  = lane & 15;
    const int kb = lane >> 4;

    floatx4 acc[8];
    #pragma unroll
    for (int t = 0; t < 8; ++t) acc[t] = (floatx4)(0.f);

    const float* xrow = x + (size_t)(n0 + m) * IN_D;

    #pragma unroll
    for (int kc = 0; kc < 4; ++kc) {
        float4 v0 = *(const float4*)(xrow + kc * 32 + kb * 8);
        float4 v1 = *(const float4*)(xrow + kc * 32 + kb * 8 + 4);
        float xs[8] = {v0.x, v0.y, v0.z, v0.w, v1.x, v1.y, v1.z, v1.w};
        bf16x8 ahi, alo;
        #pragma unroll
        for (int j = 0; j < 8; ++j) {
            __bf16 h = (__bf16)xs[j];
            ahi[j] = h;
            alo[j] = (__bf16)(xs[j] - (float)h);
        }
        #pragma unroll
        for (int nt = 0; nt < 8; ++nt) {
            int off = ((nt * 4 + kc) * 64 + lane) * 8;
            bf16x8 b = *(const bf16x8*)(sB + off);
            acc[nt] = __builtin_amdgcn_mfma_f32_16x16x32_bf16(ahi, b, acc[nt], 0, 0, 0);
            acc[nt] = __builtin_amdgcn_mfma_f32_16x16x32_bf16(alo, b, acc[nt], 0, 0, 0);
        }
    }

    // D layout: col = lane&15 (=m), row = kb*4 + reg
    #pragma unroll
    for (int nt = 0; nt < 8; ++nt) {
        int col = (nt & 3) * 16 + m;
        unsigned short* dp = (nt < 4) ? zb : zib;
        #pragma unroll
        for (int reg = 0; reg < 4; ++reg) {
            int row = n0 + kb * 4 + reg;
            __bf16 h = (__bf16)acc[nt][reg];
            dp[(size_t)row * OUT_D + col] = *(unsigned short*)&h;
        }
    }

    // s1[n] = z[n,:].Wa[0:64], s2[n] = z[n,:].Wa[64:128]  (fp32 accs)
    #pragma unroll
    for (int reg = 0; reg < 4; ++reg) {
        float p1 = 0.f, p2 = 0.f;
        #pragma unroll
        for (int nt = 0; nt < 4; ++nt) {
            float zv = acc[nt][reg];
            p1 += zv * sWa[nt * 16 + m];
            p2 += zv * sWa[64 + nt * 16 + m];
        }
        #pragma unroll
        for (int off = 8; off > 0; off >>= 1) {
            p1 += __shfl_xor(p1, off);
            p2 += __shfl_xor(p2, off);
        }
        if (m == 0) {
            int row = n0 + kb * 4 + reg;
            s1[row] = p1;
            s2[row] = p2;
        }
    }
}

// ---- K1: scan of 196 bucket counts -> bucketStart[197]; sentinels. ----
__global__ __launch_bounds__(256) void bucket_scan_kernel(
    const int* __restrict__ gh, int* __restrict__ bucketStart,
    int* __restrict__ row_start)
{
    __shared__ int s[256];
    int t = threadIdx.x;
    int v = (t < NBUCK) ? gh[t] : 0;
    s[t] = v;
    __syncthreads();
    for (int off = 1; off < 256; off <<= 1) {
        int add = (t >= off) ? s[t - off] : 0;
        __syncthreads();
        s[t] += add;
        __syncthreads();
    }
    if (t < NBUCK) bucketStart[t] = s[t] - v;     // exclusive
    if (t == NBUCK - 1) bucketStart[NBUCK] = s[t];
    if (t == 0) row_start[N_NODES] = N_EDGES;
}

// ---- K2 (pass A): bucket scatter. Per fat block: LDS count per bucket,
//          reserve a contiguous run per bucket (1 global atomic each), then
//          scatter {src|(d&511)<<17, s1[src]+tc*edge_d} into the run.
//          Runs ~334 B written by one block in a tight window -> combine. ----
__global__ __launch_bounds__(256) void passA_kernel(
    const int* __restrict__ dst, const int* __restrict__ src,
    const float* __restrict__ edge_d, const float* __restrict__ s1,
    const float* __restrict__ W0, const float* __restrict__ Wa,
    const int* __restrict__ bucketStart, int* __restrict__ gcur,
    uint2* __restrict__ payA)
{
    __shared__ int h[NBUCK];
    __shared__ int lcur[NBUCK];
    const float tc = W0[0] * Wa[2 * OUT_D];

    for (int i = threadIdx.x; i < NBUCK; i += 256) h[i] = 0;
    __syncthreads();
    int base = blockIdx.x * EPB;
    #pragma unroll 4
    for (int k = 0; k < EPB / 256; ++k) {
        int i = base + k * 256 + threadIdx.x;
        if (i < N_EDGES) atomicAdd(&h[dst[i] >> BSHIFT], 1);
    }
    __syncthreads();
    for (int b = threadIdx.x; b < NBUCK; b += 256)
        lcur[b] = bucketStart[b] + atomicAdd(&gcur[b], h[b]);
    __syncthreads();
    #pragma unroll 4
    for (int k = 0; k < EPB / 256; ++k) {
        int i = base + k * 256 + threadIdx.x;
        if (i < N_EDGES) {
            int d  = dst[i];
            int sj = src[i];
            int pos = atomicAdd(&lcur[d >> BSHIFT], 1);
            float apart = s1[sj] + tc * edge_d[i];
            payA[pos] = make_uint2((unsigned)sj | ((unsigned)(d & 511) << 17),
                                   __float_as_uint(apart));
        }
    }
}

// ---- K3 (pass B): one block per bucket. Count 512 nodes, block-scan,
//          emit row_start, rescatter within the bucket's ~50 KB region
//          (single block -> single CU -> writes combine in its L2).
//          Folds s2[d] + leaky_relu + exp: payB = {src, exp(e)}. ----
__global__ __launch_bounds__(256) void passB_kernel(
    const int* __restrict__ bucketStart, const float* __restrict__ s2,
    const uint2* __restrict__ payA, int* __restrict__ row_start,
    uint2* __restrict__ payB)
{
    __shared__ int h[512];
    __shared__ int lcur[512];
    __shared__ int sm[256];
    const int b = blockIdx.x, t = threadIdx.x;
    const int s = bucketStart[b], e = bucketStart[b + 1];
    const int n0 = b << BSHIFT;

    h[t] = 0; h[t + 256] = 0;
    __syncthreads();
    for (int i = s + t; i < e; i += 256)
        atomicAdd(&h[payA[i].x >> 17], 1);
    __syncthreads();

    int a0 = h[2 * t], a1 = h[2 * t + 1];
    sm[t] = a0 + a1;
    __syncthreads();
    for (int off = 1; off < 256; off <<= 1) {
        int add = (t >= off) ? sm[t - off] : 0;
        __syncthreads();
        sm[t] += add;
        __syncthreads();
    }
    int e0 = sm[t] - (a0 + a1);                  // exclusive over pairs
    lcur[2 * t]     = s + e0;
    lcur[2 * t + 1] = s + e0 + a0;
    int n = n0 + 2 * t;
    if (n < N_NODES)     row_start[n]     = s + e0;
    if (n + 1 < N_NODES) row_start[n + 1] = s + e0 + a0;
    __syncthreads();

    for (int i = s + t; i < e; i += 256) {
        uint2 u = payA[i];
        int j = (int)(u.x >> 17);
        int pos = atomicAdd(&lcur[j], 1);
        float a = __uint_as_float(u.y) + s2[n0 + j];
        float el = (a > 0.f) ? a : 0.01f * a;
        payB[pos] = make_uint2(u.x & 0x1FFFFu, __float_as_uint(__expf(el)));
    }
}

// ---- K4: gather. Two nodes per wave (32 lanes each), contiguous per-node
//          payload segment (no shards / no exp / no compaction). Phase B:
//          sequential 8 B load + LDS enqueue; phase C: 4 edge slots x
//          8 chunks of 16 B z-row loads. ----
__global__ __launch_bounds__(256) void gather_finalize_kernel(
    const int* __restrict__ row_start, const uint2* __restrict__ payB,
    const unsigned short* __restrict__ zb, const unsigned short* __restrict__ zib,
    float* __restrict__ out)
{
    __shared__ uint2 buf[8][32];

    const int lane = threadIdx.x & 63;
    const int wave = threadIdx.x >> 6;
    const int half = lane >> 5;
    const int lh   = lane & 31;
    const int nodeSlot = wave * 2 + half;
    const int d = blockIdx.x * 8 + nodeSlot;   // 100000 % 8 == 0

    const int beg = row_start[d];
    const int len = row_start[d + 1] - beg;

    const int eC = lh >> 3;                    // edge slot (0..3)
    const int c  = lh & 7;                     // feature chunk

    float den = 0.f;
    float2 a0 = make_float2(0.f, 0.f), a1 = a0, a2 = a0, a3 = a0;

    for (int o = 0; o < len; o += 32) {
        int rem = len - o;
        bool v = lh < rem;
        uint2 p = payB[beg + o + (v ? lh : 0)];
        den += v ? __uint_as_float(p.y) : 0.f;
        if (v) buf[nodeSlot][lh] = p;
        // same-wave LDS write->read: hardware-ordered

        int cnt = min(32, rem);
        for (int g = 0; g * 4 < cnt; ++g) {
            int j = g * 4 + eC;
            uint2 pe = buf[nodeSlot][(j < cnt) ? j : 0];
            float exe = (j < cnt) ? __uint_as_float(pe.y) : 0.f;
            uint4 zv = *(const uint4*)(zb + (size_t)pe.x * OUT_D + c * 8);
            float2 w0 = up2(zv.x), w1 = up2(zv.y), w2 = up2(zv.z), w3 = up2(zv.w);
            a0.x = fmaf(exe, w0.x, a0.x); a0.y = fmaf(exe, w0.y, a0.y);
            a1.x = fmaf(exe, w1.x, a1.x); a1.y = fmaf(exe, w1.y, a1.y);
            a2.x = fmaf(exe, w2.x, a2.x); a2.y = fmaf(exe, w2.y, a2.y);
            a3.x = fmaf(exe, w3.x, a3.x); a3.y = fmaf(exe, w3.y, a3.y);
        }
    }

    // reductions within each half-wave
    #pragma unroll
    for (int off = 16; off > 0; off >>= 1) den += __shfl_xor(den, off);
    #pragma unroll
    for (int off = 8; off <= 16; off <<= 1) {
        a0.x += __shfl_xor(a0.x, off); a0.y += __shfl_xor(a0.y, off);
        a1.x += __shfl_xor(a1.x, off); a1.y += __shfl_xor(a1.y, off);
        a2.x += __shfl_xor(a2.x, off); a2.y += __shfl_xor(a2.y, off);
        a3.x += __shfl_xor(a3.x, off); a3.y += __shfl_xor(a3.y, off);
    }

    if (lh < 8) {
        float inv = (den > 0.f) ? 1.f / den : 0.f;   // empty -> relu(zi)
        uint4 zv = *(const uint4*)(zib + (size_t)d * OUT_D + lh * 8);
        float2 w0 = up2(zv.x), w1 = up2(zv.y), w2 = up2(zv.z), w3 = up2(zv.w);
        float4 o0, o1;
        o0.x = fmaxf(w0.x + a0.x * inv, 0.f);
        o0.y = fmaxf(w0.y + a0.y * inv, 0.f);
        o0.z = fmaxf(w1.x + a1.x * inv, 0.f);
        o0.w = fmaxf(w1.y + a1.y * inv, 0.f);
        o1.x = fmaxf(w2.x + a2.x * inv, 0.f);
        o1.y = fmaxf(w2.y + a2.y * inv, 0.f);
        o1.z = fmaxf(w3.x + a3.x * inv, 0.f);
        o1.w = fmaxf(w3.y + a3.y * inv, 0.f);
        *(float4*)(out + (size_t)d * OUT_D + lh * 8)     = o0;
        *(float4*)(out + (size_t)d * OUT_D + lh * 8 + 4) = o1;
    }
}

extern "C" void kernel_launch(void* const* d_in, const int* in_sizes, int n_in,
                              void* d_out, int out_size, void* d_ws, size_t ws_size,
                              hipStream_t stream) {
    const float* node_feats = (const float*)d_in[0];
    const float* edge_d     = (const float*)d_in[1];
    const float* W0         = (const float*)d_in[2];
    const float* W1         = (const float*)d_in[3];
    const float* W2         = (const float*)d_in[4];
    const float* Wa         = (const float*)d_in[5];
    const int*   src        = (const int*)d_in[6];
    const int*   dst        = (const int*)d_in[7];
    float* out = (float*)d_out;

    // workspace layout (~47 MB), 16 B aligned sections
    char* ws = (char*)d_ws;
    uint2*  payA = (uint2*)ws;   ws += (size_t)N_EDGES * 8;
    uint2*  payB = (uint2*)ws;   ws += (size_t)N_EDGES * 8;
    unsigned short* zbuf = (unsigned short*)ws; ws += (size_t)N_NODES * OUT_D * 2;
    unsigned short* zib  = (unsigned short*)ws; ws += (size_t)N_NODES * OUT_D * 2;
    float*  s1   = (float*)ws;   ws += (size_t)N_NODES * 4;
    float*  s2   = (float*)ws;   ws += (size_t)N_NODES * 4;
    int*    row_start   = (int*)ws; ws += (size_t)(N_NODES + 16) * 4;
    int*    bucketStart = (int*)ws; ws += (NBUCK + 16) * 4;
    int*    gh   = (int*)ws;     ws += NBUCK * 4;    // gh + gcur contiguous
    int*    gcur = (int*)ws;     ws += NBUCK * 4;
    __bf16* B    = (__bf16*)ws;  ws += 16384 * 2;

    hipMemsetAsync(gh, 0, 2 * NBUCK * 4, stream);

    prep_hist_kernel<<<64 + NBLK_E, 256, 0, stream>>>(W1, W2, B, dst, gh);

    node_proj_mfma_kernel<<<(6250 + 3) / 4, 256, 0, stream>>>(
        node_feats, B, Wa, zbuf, zib, s1, s2);

    bucket_scan_kernel<<<1, 256, 0, stream>>>(gh, bucketStart, row_start);

    passA_kernel<<<NBLK_E, 256, 0, stream>>>(
        dst, src, edge_d, s1, W0, Wa, bucketStart, gcur, payA);

    passB_kernel<<<NBUCK, 256, 0, stream>>>(
        bucketStart, s2, payA, row_start, payB);

    gather_finalize_kernel<<<N_NODES / 8, 256, 0, stream>>>(
        row_start, payB, zbuf, zib, out);
}

// Round 9
// 198.760 us; speedup vs baseline: 3.6869x; 1.1719x over previous
//
#include <hip/hip_runtime.h>

#define N_NODES 100000
#define N_EDGES 1250000
#define IN_D 128
#define OUT_D 64
#define BSHIFT 8                                  // 256 nodes per bucket
#define NBUCK  391                                // ceil(100000/256)
#define CAP    4608                               // >25 sigma above mean 3197
#define EPB    8192                               // edges per passA block
#define NBLK_E ((N_EDGES + EPB - 1) / EPB)        // 153
#define NBLK_G 1563                               // ceil(6250 node-tiles / 4)

typedef __attribute__((ext_vector_type(8))) __bf16 bf16x8;
typedef __attribute__((ext_vector_type(4))) float floatx4;

__device__ __forceinline__ float2 up2(unsigned u) {   // 2 bf16 -> 2 f32
    return make_float2(__uint_as_float(u << 16),
                       __uint_as_float(u & 0xFFFF0000u));
}

// ---- Kernel A (fused): blocks [0,153): passA bucket scatter (int4 MLP,
//      fixed-capacity buckets, payload {src|(d&255)<<17, edge_d_bits}).
//      blocks [153,...): node_proj MFMA GEMM with inline W swizzle. ----
__global__ __launch_bounds__(256) void fusedA_kernel(
    const float* __restrict__ x, const float* __restrict__ W1,
    const float* __restrict__ W2, const float* __restrict__ Wa,
    const int* __restrict__ dst, const int* __restrict__ src,
    const float* __restrict__ edge_d,
    int* __restrict__ gcur, uint2* __restrict__ payA,
    unsigned short* __restrict__ zb, unsigned short* __restrict__ zib,
    float* __restrict__ s1, float* __restrict__ s2)
{
    __shared__ __bf16 sB[16384];     // 32 KB (GEMM path)
    __shared__ float  sWa[128];
    __shared__ int    h[NBUCK];      // passA path
    __shared__ int    lcur[NBUCK];

    const int t = threadIdx.x;

    if (blockIdx.x < NBLK_E) {
        // ---------------- passA ----------------
        for (int i = t; i < NBUCK; i += 256) h[i] = 0;
        __syncthreads();
        const int base = blockIdx.x * EPB;
        for (int k0 = 0; k0 < EPB; k0 += 1024) {
            int i = base + k0 + t * 4;
            if (i < N_EDGES) {                    // N_EDGES % 4 == 0
                int4 d4 = *(const int4*)(dst + i);
                atomicAdd(&h[d4.x >> BSHIFT], 1);
                atomicAdd(&h[d4.y >> BSHIFT], 1);
                atomicAdd(&h[d4.z >> BSHIFT], 1);
                atomicAdd(&h[d4.w >> BSHIFT], 1);
            }
        }
        __syncthreads();
        for (int b = t; b < NBUCK; b += 256) {
            int hc = h[b];
            int p = hc ? atomicAdd(&gcur[b], hc) : 0;
            lcur[b] = b * CAP + p;
        }
        __syncthreads();
        #define EMIT(dv, sv, ev)                                              \
            { int bk = (dv) >> BSHIFT;                                        \
              int pos = atomicAdd(&lcur[bk], 1);                              \
              if (pos < (bk + 1) * CAP)                                       \
                  payA[pos] = make_uint2((unsigned)(sv) |                     \
                                         ((unsigned)((dv) & 255) << 17),      \
                                         __float_as_uint(ev)); }
        for (int k0 = 0; k0 < EPB; k0 += 1024) {
            int i = base + k0 + t * 4;
            if (i < N_EDGES) {
                int4   d4 = *(const int4*)(dst + i);
                int4   s4 = *(const int4*)(src + i);
                float4 e4 = *(const float4*)(edge_d + i);
                EMIT(d4.x, s4.x, e4.x);
                EMIT(d4.y, s4.y, e4.y);
                EMIT(d4.z, s4.z, e4.z);
                EMIT(d4.w, s4.w, e4.w);
            }
        }
        #undef EMIT
        return;
    }

    // ---------------- node_proj (inline W swizzle) ----------------
    for (int i = t; i < 16384; i += 256) {
        int j    = i & 7;
        int lane = (i >> 3) & 63;
        int blk  = i >> 9;                  // nt*4 + kc
        int nt = blk >> 2, kc = blk & 3;
        int n = nt * 16 + (lane & 15);
        int k = kc * 32 + (lane >> 4) * 8 + j;
        float w = (n < 64) ? W1[n * 128 + k] : W2[(n - 64) * 128 + k];
        sB[i] = (__bf16)w;
    }
    if (t < 128) sWa[t] = Wa[t];
    __syncthreads();

    const int lane = t & 63;
    const int wave = t >> 6;
    const int tile = (blockIdx.x - NBLK_E) * 4 + wave;
    if (tile * 16 >= N_NODES) return;          // 100000 % 16 == 0

    const int n0 = tile * 16;
    const int m  = lane & 15;
    const int kb = lane >> 4;

    floatx4 acc[8];
    #pragma unroll
    for (int q = 0; q < 8; ++q) acc[q] = (floatx4)(0.f);

    const float* xrow = x + (size_t)(n0 + m) * IN_D;

    #pragma unroll
    for (int kc = 0; kc < 4; ++kc) {
        float4 v0 = *(const float4*)(xrow + kc * 32 + kb * 8);
        float4 v1 = *(const float4*)(xrow + kc * 32 + kb * 8 + 4);
        float xs[8] = {v0.x, v0.y, v0.z, v0.w, v1.x, v1.y, v1.z, v1.w};
        bf16x8 ahi, alo;
        #pragma unroll
        for (int j = 0; j < 8; ++j) {
            __bf16 hh = (__bf16)xs[j];
            ahi[j] = hh;
            alo[j] = (__bf16)(xs[j] - (float)hh);
        }
        #pragma unroll
        for (int nt = 0; nt < 8; ++nt) {
            int off = ((nt * 4 + kc) * 64 + lane) * 8;
            bf16x8 b = *(const bf16x8*)(sB + off);
            acc[nt] = __builtin_amdgcn_mfma_f32_16x16x32_bf16(ahi, b, acc[nt], 0, 0, 0);
            acc[nt] = __builtin_amdgcn_mfma_f32_16x16x32_bf16(alo, b, acc[nt], 0, 0, 0);
        }
    }

    // D layout: col = lane&15 (=m), row = kb*4 + reg
    #pragma unroll
    for (int nt = 0; nt < 8; ++nt) {
        int col = (nt & 3) * 16 + m;
        unsigned short* dp = (nt < 4) ? zb : zib;
        #pragma unroll
        for (int reg = 0; reg < 4; ++reg) {
            int row = n0 + kb * 4 + reg;
            __bf16 hh = (__bf16)acc[nt][reg];
            dp[(size_t)row * OUT_D + col] = *(unsigned short*)&hh;
        }
    }

    // s1[n] = z[n,:].Wa[0:64], s2[n] = z[n,:].Wa[64:128]  (fp32 accs)
    #pragma unroll
    for (int reg = 0; reg < 4; ++reg) {
        float p1 = 0.f, p2 = 0.f;
        #pragma unroll
        for (int nt = 0; nt < 4; ++nt) {
            float zv = acc[nt][reg];
            p1 += zv * sWa[nt * 16 + m];
            p2 += zv * sWa[64 + nt * 16 + m];
        }
        #pragma unroll
        for (int off = 8; off > 0; off >>= 1) {
            p1 += __shfl_xor(p1, off);
            p2 += __shfl_xor(p2, off);
        }
        if (m == 0) {
            int row = n0 + kb * 4 + reg;
            s1[row] = p1;
            s2[row] = p2;
        }
    }
}

// ---- Kernel B (passB): one block per bucket (256 nodes). Count, scan,
//      emit node_meta{start,len}, rescatter with folded s1+s2+leaky+exp:
//      payB = {src, exp(e)}. 2-entry MLP via uint4 loads. ----
__global__ __launch_bounds__(256) void passB_kernel(
    const int* __restrict__ gcur, const float* __restrict__ s1,
    const float* __restrict__ s2, const float* __restrict__ W0,
    const float* __restrict__ Wa, const uint2* __restrict__ payA,
    int2* __restrict__ node_meta, uint2* __restrict__ payB)
{
    __shared__ int   h[256];
    __shared__ int   lc[256];
    __shared__ int   sm[256];
    __shared__ float s2s[256];

    const int b = blockIdx.x, t = threadIdx.x;
    const int base = b * CAP;
    const int cnt = min(gcur[b], CAP);
    const int n0 = b << BSHIFT;
    const float tc = W0[0] * Wa[2 * OUT_D];

    h[t] = 0;
    s2s[t] = (n0 + t < N_NODES) ? s2[n0 + t] : 0.f;
    __syncthreads();

    for (int i0 = t * 2; i0 < cnt; i0 += 512) {
        uint4 u = *(const uint4*)(payA + base + i0);   // i0 even, CAP even
        atomicAdd(&h[(u.x >> 17) & 255], 1);
        if (i0 + 1 < cnt) atomicAdd(&h[(u.z >> 17) & 255], 1);
    }
    __syncthreads();

    int v = h[t];
    sm[t] = v;
    __syncthreads();
    for (int off = 1; off < 256; off <<= 1) {
        int add = (t >= off) ? sm[t - off] : 0;
        __syncthreads();
        sm[t] += add;
        __syncthreads();
    }
    int start = base + sm[t] - v;   // exclusive within bucket
    lc[t] = start;
    if (n0 + t < N_NODES) node_meta[n0 + t] = make_int2(start, v);
    __syncthreads();

    for (int i0 = t * 2; i0 < cnt; i0 += 512) {
        uint4 u = *(const uint4*)(payA + base + i0);
        bool v2 = (i0 + 1 < cnt);
        int sj0 = u.x & 0x1FFFF;
        int sj1 = u.z & 0x1FFFF;
        float s1a = s1[sj0];
        float s1b = v2 ? s1[sj1] : 0.f;

        int j0 = (u.x >> 17) & 255;
        float a0 = fmaf(tc, __uint_as_float(u.y), s1a + s2s[j0]);
        float e0 = (a0 > 0.f) ? a0 : 0.01f * a0;
        int p0 = atomicAdd(&lc[j0], 1);
        payB[p0] = make_uint2((unsigned)sj0, __float_as_uint(__expf(e0)));

        if (v2) {
            int j1 = (u.z >> 17) & 255;
            float a1 = fmaf(tc, __uint_as_float(u.w), s1b + s2s[j1]);
            float e1 = (a1 > 0.f) ? a1 : 0.01f * a1;
            int p1 = atomicAdd(&lc[j1], 1);
            payB[p1] = make_uint2((unsigned)sj1, __float_as_uint(__expf(e1)));
        }
    }
}

// ---- Kernel C: gather. Two nodes per wave (32 lanes each); contiguous
//      per-node payB segment via node_meta; phase B: sequential 8 B load +
//      LDS enqueue; phase C: 4 edge slots x 8 chunks of 16 B z loads. ----
__global__ __launch_bounds__(256) void gather_finalize_kernel(
    const int2* __restrict__ node_meta, const uint2* __restrict__ payB,
    const unsigned short* __restrict__ zb, const unsigned short* __restrict__ zib,
    float* __restrict__ out)
{
    __shared__ uint2 buf[8][32];

    const int lane = threadIdx.x & 63;
    const int wave = threadIdx.x >> 6;
    const int half = lane >> 5;
    const int lh   = lane & 31;
    const int nodeSlot = wave * 2 + half;
    const int d = blockIdx.x * 8 + nodeSlot;   // 100000 % 8 == 0

    const int2 meta = node_meta[d];
    const int beg = meta.x;
    const int len = meta.y;

    const int eC = lh >> 3;                    // edge slot (0..3)
    const int c  = lh & 7;                     // feature chunk

    float den = 0.f;
    float2 a0 = make_float2(0.f, 0.f), a1 = a0, a2 = a0, a3 = a0;

    for (int o = 0; o < len; o += 32) {
        int rem = len - o;
        bool v = lh < rem;
        uint2 p = payB[beg + o + (v ? lh : 0)];
        den += v ? __uint_as_float(p.y) : 0.f;
        if (v) buf[nodeSlot][lh] = p;
        // same-wave LDS write->read: hardware-ordered

        int cnt = min(32, rem);
        for (int g = 0; g * 4 < cnt; ++g) {
            int j = g * 4 + eC;
            uint2 pe = buf[nodeSlot][(j < cnt) ? j : 0];
            float exe = (j < cnt) ? __uint_as_float(pe.y) : 0.f;
            uint4 zv = *(const uint4*)(zb + (size_t)pe.x * OUT_D + c * 8);
            float2 w0 = up2(zv.x), w1 = up2(zv.y), w2 = up2(zv.z), w3 = up2(zv.w);
            a0.x = fmaf(exe, w0.x, a0.x); a0.y = fmaf(exe, w0.y, a0.y);
            a1.x = fmaf(exe, w1.x, a1.x); a1.y = fmaf(exe, w1.y, a1.y);
            a2.x = fmaf(exe, w2.x, a2.x); a2.y = fmaf(exe, w2.y, a2.y);
            a3.x = fmaf(exe, w3.x, a3.x); a3.y = fmaf(exe, w3.y, a3.y);
        }
    }

    // reductions within each half-wave
    #pragma unroll
    for (int off = 16; off > 0; off >>= 1) den += __shfl_xor(den, off);
    #pragma unroll
    for (int off = 8; off <= 16; off <<= 1) {
        a0.x += __shfl_xor(a0.x, off); a0.y += __shfl_xor(a0.y, off);
        a1.x += __shfl_xor(a1.x, off); a1.y += __shfl_xor(a1.y, off);
        a2.x += __shfl_xor(a2.x, off); a2.y += __shfl_xor(a2.y, off);
        a3.x += __shfl_xor(a3.x, off); a3.y += __shfl_xor(a3.y, off);
    }

    if (lh < 8) {
        float inv = (den > 0.f) ? 1.f / den : 0.f;   // empty -> relu(zi)
        uint4 zv = *(const uint4*)(zib + (size_t)d * OUT_D + lh * 8);
        float2 w0 = up2(zv.x), w1 = up2(zv.y), w2 = up2(zv.z), w3 = up2(zv.w);
        float4 o0, o1;
        o0.x = fmaxf(w0.x + a0.x * inv, 0.f);
        o0.y = fmaxf(w0.y + a0.y * inv, 0.f);
        o0.z = fmaxf(w1.x + a1.x * inv, 0.f);
        o0.w = fmaxf(w1.y + a1.y * inv, 0.f);
        o1.x = fmaxf(w2.x + a2.x * inv, 0.f);
        o1.y = fmaxf(w2.y + a2.y * inv, 0.f);
        o1.z = fmaxf(w3.x + a3.x * inv, 0.f);
        o1.w = fmaxf(w3.y + a3.y * inv, 0.f);
        *(float4*)(out + (size_t)d * OUT_D + lh * 8)     = o0;
        *(float4*)(out + (size_t)d * OUT_D + lh * 8 + 4) = o1;
    }
}

extern "C" void kernel_launch(void* const* d_in, const int* in_sizes, int n_in,
                              void* d_out, int out_size, void* d_ws, size_t ws_size,
                              hipStream_t stream) {
    const float* node_feats = (const float*)d_in[0];
    const float* edge_d     = (const float*)d_in[1];
    const float* W0         = (const float*)d_in[2];
    const float* W1         = (const float*)d_in[3];
    const float* W2         = (const float*)d_in[4];
    const float* Wa         = (const float*)d_in[5];
    const int*   src        = (const int*)d_in[6];
    const int*   dst        = (const int*)d_in[7];
    float* out = (float*)d_out;

    // workspace layout (~56.5 MB), 16 B aligned sections
    char* ws = (char*)d_ws;
    uint2* payA = (uint2*)ws;    ws += (size_t)NBUCK * CAP * 8;   // 14.4 MB
    uint2* payB = (uint2*)ws;    ws += (size_t)NBUCK * CAP * 8;   // 14.4 MB
    unsigned short* zbuf = (unsigned short*)ws; ws += (size_t)N_NODES * OUT_D * 2;
    unsigned short* zib  = (unsigned short*)ws; ws += (size_t)N_NODES * OUT_D * 2;
    float* s1 = (float*)ws;      ws += (size_t)N_NODES * 4;
    float* s2 = (float*)ws;      ws += (size_t)N_NODES * 4;
    int2*  node_meta = (int2*)ws; ws += (size_t)N_NODES * 8;
    int*   gcur = (int*)ws;      ws += ((NBUCK + 3) & ~3) * 4;

    hipMemsetAsync(gcur, 0, NBUCK * 4, stream);

    fusedA_kernel<<<NBLK_E + NBLK_G, 256, 0, stream>>>(
        node_feats, W1, W2, Wa, dst, src, edge_d,
        gcur, payA, zbuf, zib, s1, s2);

    passB_kernel<<<NBUCK, 256, 0, stream>>>(
        gcur, s1, s2, W0, Wa, payA, node_meta, payB);

    gather_finalize_kernel<<<N_NODES / 8, 256, 0, stream>>>(
        node_meta, payB, zbuf, zib, out);
}

// Round 10
// 191.195 us; speedup vs baseline: 3.8328x; 1.0396x over previous
//
#include <hip/hip_runtime.h>

#define N_NODES 100000
#define N_EDGES 1250000
#define IN_D 128
#define OUT_D 64
#define BSHIFT 8                                  // 256 nodes per bucket
#define NBUCK  391                                // ceil(100000/256)
#define CAP    4608                               // mean 3200 + 25 sigma
#define EPB    4096                               // edges per passA block
#define NBLK_E 306                                // ceil(1250000/4096)
#define NBLK_G 1563                               // ceil(6250 node-tiles / 4)

typedef __attribute__((ext_vector_type(8))) __bf16 bf16x8;
typedef __attribute__((ext_vector_type(4))) float floatx4;

__device__ __forceinline__ float2 up2(unsigned u) {   // 2 bf16 -> 2 f32
    return make_float2(__uint_as_float(u << 16),
                       __uint_as_float(u & 0xFFFF0000u));
}

// ---- Kernel A (fused): blocks [0,306): passA bucket scatter (int4 MLP,
//      fixed-capacity buckets, payload {src|(d&255)<<17, tc*edge_d}).
//      blocks [306,...): node_proj MFMA GEMM, vectorized in-reg W swizzle. ----
__global__ __launch_bounds__(256) void fusedA_kernel(
    const float* __restrict__ x, const float* __restrict__ W1,
    const float* __restrict__ W2, const float* __restrict__ W0,
    const float* __restrict__ Wa,
    const int* __restrict__ dst, const int* __restrict__ src,
    const float* __restrict__ edge_d,
    int* __restrict__ gcur, uint2* __restrict__ payA,
    unsigned short* __restrict__ zb, unsigned short* __restrict__ zib,
    float* __restrict__ s1, float* __restrict__ s2)
{
    __shared__ __bf16 sB[16384];     // 32 KB (GEMM path)
    __shared__ float  sWa[128];
    __shared__ int    h[NBUCK];      // passA path
    __shared__ int    lcur[NBUCK];

    const int t = threadIdx.x;

    if (blockIdx.x < NBLK_E) {
        // ---------------- passA ----------------
        const float tc = W0[0] * Wa[2 * OUT_D];
        for (int i = t; i < NBUCK; i += 256) h[i] = 0;
        __syncthreads();
        const int base = blockIdx.x * EPB;
        for (int k0 = 0; k0 < EPB; k0 += 1024) {
            int i = base + k0 + t * 4;
            if (i < N_EDGES) {                    // N_EDGES % 4 == 0
                int4 d4 = *(const int4*)(dst + i);
                atomicAdd(&h[d4.x >> BSHIFT], 1);
                atomicAdd(&h[d4.y >> BSHIFT], 1);
                atomicAdd(&h[d4.z >> BSHIFT], 1);
                atomicAdd(&h[d4.w >> BSHIFT], 1);
            }
        }
        __syncthreads();
        for (int b = t; b < NBUCK; b += 256) {
            int hc = h[b];
            int p = hc ? atomicAdd(&gcur[b], hc) : 0;
            lcur[b] = b * CAP + p;
        }
        __syncthreads();
        #define EMIT(dv, sv, ev)                                              \
            { int bk = (dv) >> BSHIFT;                                        \
              int pos = atomicAdd(&lcur[bk], 1);                              \
              if (pos < (bk + 1) * CAP)                                       \
                  payA[pos] = make_uint2((unsigned)(sv) |                     \
                                         ((unsigned)((dv) & 255) << 17),      \
                                         __float_as_uint(tc * (ev))); }
        for (int k0 = 0; k0 < EPB; k0 += 1024) {
            int i = base + k0 + t * 4;
            if (i < N_EDGES) {
                int4   d4 = *(const int4*)(dst + i);
                int4   s4 = *(const int4*)(src + i);
                float4 e4 = *(const float4*)(edge_d + i);
                EMIT(d4.x, s4.x, e4.x);
                EMIT(d4.y, s4.y, e4.y);
                EMIT(d4.z, s4.z, e4.z);
                EMIT(d4.w, s4.w, e4.w);
            }
        }
        #undef EMIT
        return;
    }

    // ------- node_proj: vectorized W swizzle (8 groups/thread) -------
    // group gi = n*16 + k8: read W[n][k8*8 .. +7], write one bf16x8 to the
    // fragment slot ((nt*4+kc)*64 + lane)*8, lane = ((k8&3)<<4)|(n&15).
    #pragma unroll
    for (int g = 0; g < 8; ++g) {
        int gi = t + g * 256;            // 0..2047
        int n  = gi >> 4;
        int k8 = gi & 15;
        const float* wrow = (n < 64) ? (W1 + n * 128) : (W2 + (n - 64) * 128);
        float4 v0 = *(const float4*)(wrow + k8 * 8);
        float4 v1 = *(const float4*)(wrow + k8 * 8 + 4);
        int lane = ((k8 & 3) << 4) | (n & 15);
        int off  = (((n >> 4) * 4 + (k8 >> 2)) * 64 + lane) * 8;
        bf16x8 bb;
        bb[0] = (__bf16)v0.x; bb[1] = (__bf16)v0.y;
        bb[2] = (__bf16)v0.z; bb[3] = (__bf16)v0.w;
        bb[4] = (__bf16)v1.x; bb[5] = (__bf16)v1.y;
        bb[6] = (__bf16)v1.z; bb[7] = (__bf16)v1.w;
        *(bf16x8*)(sB + off) = bb;
    }
    if (t < 128) sWa[t] = Wa[t];
    __syncthreads();

    const int lane = t & 63;
    const int wave = t >> 6;
    const int tile = (blockIdx.x - NBLK_E) * 4 + wave;
    if (tile * 16 >= N_NODES) return;          // 100000 % 16 == 0

    const int n0 = tile * 16;
    const int m  = lane & 15;
    const int kb = lane >> 4;

    floatx4 acc[8];
    #pragma unroll
    for (int q = 0; q < 8; ++q) acc[q] = (floatx4)(0.f);

    const float* xrow = x + (size_t)(n0 + m) * IN_D;

    #pragma unroll
    for (int kc = 0; kc < 4; ++kc) {
        float4 v0 = *(const float4*)(xrow + kc * 32 + kb * 8);
        float4 v1 = *(const float4*)(xrow + kc * 32 + kb * 8 + 4);
        float xs[8] = {v0.x, v0.y, v0.z, v0.w, v1.x, v1.y, v1.z, v1.w};
        bf16x8 ahi, alo;
        #pragma unroll
        for (int j = 0; j < 8; ++j) {
            __bf16 hh = (__bf16)xs[j];
            ahi[j] = hh;
            alo[j] = (__bf16)(xs[j] - (float)hh);
        }
        #pragma unroll
        for (int nt = 0; nt < 8; ++nt) {
            int off = ((nt * 4 + kc) * 64 + lane) * 8;
            bf16x8 b = *(const bf16x8*)(sB + off);
            acc[nt] = __builtin_amdgcn_mfma_f32_16x16x32_bf16(ahi, b, acc[nt], 0, 0, 0);
            acc[nt] = __builtin_amdgcn_mfma_f32_16x16x32_bf16(alo, b, acc[nt], 0, 0, 0);
        }
    }

    // D layout: col = lane&15 (=m), row = kb*4 + reg
    #pragma unroll
    for (int nt = 0; nt < 8; ++nt) {
        int col = (nt & 3) * 16 + m;
        unsigned short* dp = (nt < 4) ? zb : zib;
        #pragma unroll
        for (int reg = 0; reg < 4; ++reg) {
            int row = n0 + kb * 4 + reg;
            __bf16 hh = (__bf16)acc[nt][reg];
            dp[(size_t)row * OUT_D + col] = *(unsigned short*)&hh;
        }
    }

    // s1[n] = z[n,:].Wa[0:64], s2[n] = z[n,:].Wa[64:128]  (fp32 accs)
    #pragma unroll
    for (int reg = 0; reg < 4; ++reg) {
        float p1 = 0.f, p2 = 0.f;
        #pragma unroll
        for (int nt = 0; nt < 4; ++nt) {
            float zv = acc[nt][reg];
            p1 += zv * sWa[nt * 16 + m];
            p2 += zv * sWa[64 + nt * 16 + m];
        }
        #pragma unroll
        for (int off = 8; off > 0; off >>= 1) {
            p1 += __shfl_xor(p1, off);
            p2 += __shfl_xor(p2, off);
        }
        if (m == 0) {
            int row = n0 + kb * 4 + reg;
            s1[row] = p1;
            s2[row] = p2;
        }
    }
}

// ---- Kernel B (passB): pure permutation, one block per bucket (256 nodes),
//      512 threads, 4-entry MLP. Count, scan, emit node_meta{start,len},
//      rescatter payB = {src, tc*edge_d} into per-node contiguous runs. ----
__global__ __launch_bounds__(512) void passB_kernel(
    const int* __restrict__ gcur, const uint2* __restrict__ payA,
    int2* __restrict__ node_meta, uint2* __restrict__ payB)
{
    __shared__ int h[256];
    __shared__ int lc[256];
    __shared__ int sm[256];

    const int b = blockIdx.x, t = threadIdx.x;
    const int base = b * CAP;
    const int cnt = min(gcur[b], CAP);
    const int n0 = b << BSHIFT;

    if (t < 256) h[t] = 0;
    __syncthreads();

    for (int i0 = t * 4; i0 < cnt; i0 += 2048) {
        uint4 u0 = *(const uint4*)(payA + base + i0);       // 16B aligned
        uint4 u1 = *(const uint4*)(payA + base + i0 + 2);   // safe: region padded to CAP
        atomicAdd(&h[(u0.x >> 17) & 255], 1);
        if (i0 + 1 < cnt) atomicAdd(&h[(u0.z >> 17) & 255], 1);
        if (i0 + 2 < cnt) atomicAdd(&h[(u1.x >> 17) & 255], 1);
        if (i0 + 3 < cnt) atomicAdd(&h[(u1.z >> 17) & 255], 1);
    }
    __syncthreads();

    if (t < 256) {
        int v = h[t];
        sm[t] = v;
        __syncthreads();
        for (int off = 1; off < 256; off <<= 1) {
            int add = (t >= off) ? sm[t - off] : 0;
            __syncthreads();
            sm[t] += add;
            __syncthreads();
        }
        int start = base + sm[t] - v;
        lc[t] = start;
        if (n0 + t < N_NODES) node_meta[n0 + t] = make_int2(start, v);
    } else {
        __syncthreads();
        for (int off = 1; off < 256; off <<= 1) {
            __syncthreads(); __syncthreads();
        }
    }
    __syncthreads();

    #define PUT(xx, yy, ok)                                                   \
        if (ok) { int j = ((xx) >> 17) & 255;                                 \
                  int pos = atomicAdd(&lc[j], 1);                             \
                  payB[pos] = make_uint2((xx) & 0x1FFFFu, (yy)); }
    for (int i0 = t * 4; i0 < cnt; i0 += 2048) {
        uint4 u0 = *(const uint4*)(payA + base + i0);
        uint4 u1 = *(const uint4*)(payA + base + i0 + 2);
        PUT(u0.x, u0.y, true);
        PUT(u0.z, u0.w, i0 + 1 < cnt);
        PUT(u1.x, u1.y, i0 + 2 < cnt);
        PUT(u1.z, u1.w, i0 + 3 < cnt);
    }
    #undef PUT
}

// ---- Kernel C: gather. Two nodes per wave (32 lanes each); per-node
//      contiguous payB via node_meta. Phase B: payB load + s1 gather +
//      leaky + exp + LDS enqueue {src, ex}; phase C: 4 edge slots x
//      8 chunks of 16 B z loads. ----
__global__ __launch_bounds__(256) void gather_finalize_kernel(
    const int2* __restrict__ node_meta, const uint2* __restrict__ payB,
    const float* __restrict__ s1, const float* __restrict__ s2,
    const unsigned short* __restrict__ zb, const unsigned short* __restrict__ zib,
    float* __restrict__ out)
{
    __shared__ uint2 buf[8][32];

    const int lane = threadIdx.x & 63;
    const int wave = threadIdx.x >> 6;
    const int half = lane >> 5;
    const int lh   = lane & 31;
    const int nodeSlot = wave * 2 + half;
    const int d = blockIdx.x * 8 + nodeSlot;   // 100000 % 8 == 0

    const int2 meta = node_meta[d];
    const int beg = meta.x;
    const int len = meta.y;
    const float s2d = s2[d];

    const int eC = lh >> 3;                    // edge slot (0..3)
    const int c  = lh & 7;                     // feature chunk

    float den = 0.f;
    float2 a0 = make_float2(0.f, 0.f), a1 = a0, a2 = a0, a3 = a0;

    for (int o = 0; o < len; o += 32) {
        int rem = len - o;
        bool v = lh < rem;
        uint2 p = payB[beg + o + (v ? lh : 0)];
        float ex = 0.f;
        if (v) {
            float a = __uint_as_float(p.y) + s1[p.x] + s2d;
            float e = (a > 0.f) ? a : 0.01f * a;
            ex = __expf(e);
            buf[nodeSlot][lh] = make_uint2(p.x, __float_as_uint(ex));
        }
        den += ex;
        // same-wave LDS write->read: hardware-ordered

        int cnt = min(32, rem);
        for (int g = 0; g * 4 < cnt; ++g) {
            int j = g * 4 + eC;
            uint2 pe = buf[nodeSlot][(j < cnt) ? j : 0];
            float exe = (j < cnt) ? __uint_as_float(pe.y) : 0.f;
            uint4 zv = *(const uint4*)(zb + (size_t)pe.x * OUT_D + c * 8);
            float2 w0 = up2(zv.x), w1 = up2(zv.y), w2 = up2(zv.z), w3 = up2(zv.w);
            a0.x = fmaf(exe, w0.x, a0.x); a0.y = fmaf(exe, w0.y, a0.y);
            a1.x = fmaf(exe, w1.x, a1.x); a1.y = fmaf(exe, w1.y, a1.y);
            a2.x = fmaf(exe, w2.x, a2.x); a2.y = fmaf(exe, w2.y, a2.y);
            a3.x = fmaf(exe, w3.x, a3.x); a3.y = fmaf(exe, w3.y, a3.y);
        }
    }

    // reductions within each half-wave
    #pragma unroll
    for (int off = 16; off > 0; off >>= 1) den += __shfl_xor(den, off);
    #pragma unroll
    for (int off = 8; off <= 16; off <<= 1) {
        a0.x += __shfl_xor(a0.x, off); a0.y += __shfl_xor(a0.y, off);
        a1.x += __shfl_xor(a1.x, off); a1.y += __shfl_xor(a1.y, off);
        a2.x += __shfl_xor(a2.x, off); a2.y += __shfl_xor(a2.y, off);
        a3.x += __shfl_xor(a3.x, off); a3.y += __shfl_xor(a3.y, off);
    }

    if (lh < 8) {
        float inv = (den > 0.f) ? 1.f / den : 0.f;   // empty -> relu(zi)
        uint4 zv = *(const uint4*)(zib + (size_t)d * OUT_D + lh * 8);
        float2 w0 = up2(zv.x), w1 = up2(zv.y), w2 = up2(zv.z), w3 = up2(zv.w);
        float4 o0, o1;
        o0.x = fmaxf(w0.x + a0.x * inv, 0.f);
        o0.y = fmaxf(w0.y + a0.y * inv, 0.f);
        o0.z = fmaxf(w1.x + a1.x * inv, 0.f);
        o0.w = fmaxf(w1.y + a1.y * inv, 0.f);
        o1.x = fmaxf(w2.x + a2.x * inv, 0.f);
        o1.y = fmaxf(w2.y + a2.y * inv, 0.f);
        o1.z = fmaxf(w3.x + a3.x * inv, 0.f);
        o1.w = fmaxf(w3.y + a3.y * inv, 0.f);
        *(float4*)(out + (size_t)d * OUT_D + lh * 8)     = o0;
        *(float4*)(out + (size_t)d * OUT_D + lh * 8 + 4) = o1;
    }
}

extern "C" void kernel_launch(void* const* d_in, const int* in_sizes, int n_in,
                              void* d_out, int out_size, void* d_ws, size_t ws_size,
                              hipStream_t stream) {
    const float* node_feats = (const float*)d_in[0];
    const float* edge_d     = (const float*)d_in[1];
    const float* W0         = (const float*)d_in[2];
    const float* W1         = (const float*)d_in[3];
    const float* W2         = (const float*)d_in[4];
    const float* Wa         = (const float*)d_in[5];
    const int*   src        = (const int*)d_in[6];
    const int*   dst        = (const int*)d_in[7];
    float* out = (float*)d_out;

    // workspace layout (~56.5 MB), 16 B aligned sections
    char* ws = (char*)d_ws;
    uint2* payA = (uint2*)ws;    ws += (size_t)NBUCK * CAP * 8;   // 14.4 MB
    uint2* payB = (uint2*)ws;    ws += (size_t)NBUCK * CAP * 8;   // 14.4 MB
    unsigned short* zbuf = (unsigned short*)ws; ws += (size_t)N_NODES * OUT_D * 2;
    unsigned short* zib  = (unsigned short*)ws; ws += (size_t)N_NODES * OUT_D * 2;
    float* s1 = (float*)ws;      ws += (size_t)N_NODES * 4;
    float* s2 = (float*)ws;      ws += (size_t)N_NODES * 4;
    int2*  node_meta = (int2*)ws; ws += (size_t)N_NODES * 8;
    int*   gcur = (int*)ws;      ws += ((NBUCK + 3) & ~3) * 4;

    hipMemsetAsync(gcur, 0, NBUCK * 4, stream);

    fusedA_kernel<<<NBLK_E + NBLK_G, 256, 0, stream>>>(
        node_feats, W1, W2, W0, Wa, dst, src, edge_d,
        gcur, payA, zbuf, zib, s1, s2);

    passB_kernel<<<NBUCK, 512, 0, stream>>>(gcur, payA, node_meta, payB);

    gather_finalize_kernel<<<N_NODES / 8, 256, 0, stream>>>(
        node_meta, payB, s1, s2, zbuf, zib, out);
}